// Round 1
// baseline (1446.211 us; speedup 1.0000x reference)
//
#include <hip/hip_runtime.h>
#include <hip/hip_bf16.h>
#include <math.h>

#define NN 20000
#define NE 320000
#define NG 128

static __device__ __forceinline__ float lrelu(float v){ return v > 0.f ? v : 0.2f*v; }

// ---------------- CSR build ----------------
__global__ void k_hist(const int* __restrict__ idx, int n, int* __restrict__ cnt){
  int i = blockIdx.x*blockDim.x + threadIdx.x;
  if (i < n) atomicAdd(&cnt[idx[i]], 1);
}

// single-block exclusive scan: ptr[0]=0, ptr[i+1]=ptr[i]+deg[i]
__global__ void k_scan(const int* __restrict__ deg, int* __restrict__ ptr, int n){
  __shared__ int tmp[1024];
  __shared__ int carry;
  int t = threadIdx.x;
  if (t == 0){ carry = 0; ptr[0] = 0; }
  __syncthreads();
  for (int c0 = 0; c0 < n; c0 += 1024){
    int v = (c0 + t < n) ? deg[c0 + t] : 0;
    tmp[t] = v; __syncthreads();
    for (int off = 1; off < 1024; off <<= 1){
      int u = (t >= off) ? tmp[t - off] : 0;
      __syncthreads();
      tmp[t] += u;
      __syncthreads();
    }
    if (c0 + t < n) ptr[c0 + t + 1] = carry + tmp[t];
    __syncthreads();
    if (t == 0) carry += tmp[1023];
    __syncthreads();
  }
}

__global__ void k_fill(const int* __restrict__ src, const int* __restrict__ dst,
                       const int* __restrict__ ptr, int* __restrict__ cnt,
                       int* __restrict__ csrc){
  int e = blockIdx.x*blockDim.x + threadIdx.x;
  if (e < NE){
    int d = dst[e];
    int p = atomicAdd(&cnt[d], 1);
    csrc[ptr[d] + p] = src[e];
  }
}

// ---------------- GIN aggregation: z[n] = h[n] + sum_{in-edges} h[src] ----------------
__global__ void k_gin_agg(const float* __restrict__ h, const int* __restrict__ ptr,
                          const int* __restrict__ csrc, float* __restrict__ z, int D){
  int n = blockIdx.x;
  int t = threadIdx.x, B = blockDim.x;
  int beg = ptr[n], deg = ptr[n+1] - beg;
  __shared__ int es[256];
  bool two = (D > B);
  float a0 = h[(size_t)n*D + t];
  float a1 = two ? h[(size_t)n*D + B + t] : 0.f;
  for (int c0 = 0; c0 < deg; c0 += 256){
    int ce = min(256, deg - c0);
    for (int i = t; i < ce; i += B) es[i] = csrc[beg + c0 + i];
    __syncthreads();
    for (int i = 0; i < ce; i++){
      const float* row = h + (size_t)es[i]*D;
      a0 += row[t];
      if (two) a1 += row[B + t];
    }
    __syncthreads();
  }
  z[(size_t)n*D + t] = a0;
  if (two) z[(size_t)n*D + B + t] = a1;
}

// ---------------- fp32 tiled GEMM: C = act(A@B + bias), A[M,K], B[K,N] row-major ----------------
template<int ACT>
__global__ __launch_bounds__(256)
void k_gemm(const float* __restrict__ A, const float* __restrict__ B,
            const float* __restrict__ bias, float* __restrict__ C,
            int M, int Nn, int K){
  __shared__ float As[16][68];
  __shared__ float Bs[16][68];
  int bm = blockIdx.y*64, bn = blockIdx.x*64;
  int tid = threadIdx.x;
  int tm = (tid >> 4) << 2, tn = (tid & 15) << 2;
  float acc[4][4] = {};
  for (int k0 = 0; k0 < K; k0 += 16){
    #pragma unroll
    for (int i = 0; i < 4; i++){
      int idx = tid + i*256;
      int m = idx >> 4, k = idx & 15;
      int gm = bm + m;
      As[k][m] = (gm < M) ? A[(size_t)gm*K + k0 + k] : 0.f;
    }
    #pragma unroll
    for (int i = 0; i < 4; i++){
      int idx = tid + i*256;
      int k = idx >> 6, n = idx & 63;
      Bs[k][n] = B[(size_t)(k0 + k)*Nn + bn + n];
    }
    __syncthreads();
    #pragma unroll
    for (int k = 0; k < 16; k++){
      float a[4], b[4];
      #pragma unroll
      for (int i = 0; i < 4; i++) a[i] = As[k][tm + i];
      #pragma unroll
      for (int j = 0; j < 4; j++) b[j] = Bs[k][tn + j];
      #pragma unroll
      for (int i = 0; i < 4; i++)
        #pragma unroll
        for (int j = 0; j < 4; j++) acc[i][j] += a[i]*b[j];
    }
    __syncthreads();
  }
  #pragma unroll
  for (int i = 0; i < 4; i++){
    int gm = bm + tm + i;
    if (gm < M){
      #pragma unroll
      for (int j = 0; j < 4; j++){
        float v = acc[i][j] + (bias ? bias[bn + tn + j] : 0.f);
        if (ACT) v = fmaxf(v, 0.f);
        C[(size_t)gm*Nn + bn + tn + j] = v;
      }
    }
  }
}

// ---------------- BatchNorm ----------------
__global__ void k_bn_stats(const float* __restrict__ h, int n, int d, double* __restrict__ stats){
  int r0 = blockIdx.x*64;
  int rend = min(n, r0 + 64);
  for (int f = threadIdx.x; f < d; f += blockDim.x){
    float s = 0.f, q = 0.f;
    for (int r = r0; r < rend; r++){ float v = h[(size_t)r*d + f]; s += v; q += v*v; }
    atomicAdd(&stats[f], (double)s);
    atomicAdd(&stats[d + f], (double)q);
  }
}

__global__ void k_bn_finalize(const double* __restrict__ stats, const float* __restrict__ g,
                              const float* __restrict__ b, float* __restrict__ scale,
                              float* __restrict__ shift, int d){
  int f = blockIdx.x*blockDim.x + threadIdx.x;
  if (f >= d) return;
  double inv = 1.0 / (double)NN;
  double mu  = stats[f]*inv;
  double var = stats[d + f]*inv - mu*mu;
  if (var < 0.0) var = 0.0;
  float sc = g[f] * rsqrtf((float)var + 1e-5f);
  scale[f] = sc;
  shift[f] = b[f] - (float)mu*sc;
}

__global__ void k_bn_relu(float* __restrict__ h, int total, int dmask,
                          const float* __restrict__ scale, const float* __restrict__ shift){
  int i = blockIdx.x*blockDim.x + threadIdx.x;
  if (i < total){
    int f = i & dmask;
    float v = h[i]*scale[f] + shift[f];
    h[i] = fmaxf(v, 0.f);
  }
}

// ---------------- GAT ----------------
__global__ void k_gat_scores(const float* __restrict__ xh, const float* __restrict__ asrc,
                             const float* __restrict__ adst, float* __restrict__ a_s,
                             float* __restrict__ a_d){
  int n = blockIdx.x, l = threadIdx.x;
  const float* row = xh + (size_t)n*1024;
  for (int hd = 0; hd < 8; hd++){
    float x0 = row[hd*128 + l], x1 = row[hd*128 + 64 + l];
    float ps = x0*asrc[hd*128 + l] + x1*asrc[hd*128 + 64 + l];
    float pd = x0*adst[hd*128 + l] + x1*adst[hd*128 + 64 + l];
    #pragma unroll
    for (int off = 32; off > 0; off >>= 1){ ps += __shfl_down(ps, off); pd += __shfl_down(pd, off); }
    if (l == 0){ a_s[n*8 + hd] = ps; a_d[n*8 + hd] = pd; }
  }
}

__global__ __launch_bounds__(128)
void k_gat_node(const float* __restrict__ xh, const float* __restrict__ a_s,
                const float* __restrict__ a_d, const int* __restrict__ ptr,
                const int* __restrict__ csrc, const float* __restrict__ bias,
                float* __restrict__ hout){
  int n = blockIdx.x, t = threadIdx.x;
  int beg = ptr[n], deg = ptr[n+1] - beg;
  int tot = deg + 1;                       // + self-loop
  __shared__ float red[128];
  __shared__ float ms[8], ss[8], adn[8];
  __shared__ float alpha[128][8];
  __shared__ int esrc[128];
  if (t < 8) adn[t] = a_d[n*8 + t];
  __syncthreads();
  int head = t & 7, slot = t >> 3;
  float mx = -1e30f;
  for (int e = slot; e < tot; e += 16){
    int s = (e < deg) ? csrc[beg + e] : n;
    mx = fmaxf(mx, lrelu(a_s[s*8 + head] + adn[head]));
  }
  red[t] = mx; __syncthreads();
  for (int off = 64; off >= 8; off >>= 1){ if (t < off) red[t] = fmaxf(red[t], red[t + off]); __syncthreads(); }
  if (t < 8) ms[t] = red[t];
  __syncthreads();
  float sm = 0.f;
  for (int e = slot; e < tot; e += 16){
    int s = (e < deg) ? csrc[beg + e] : n;
    sm += __expf(lrelu(a_s[s*8 + head] + adn[head]) - ms[head]);
  }
  red[t] = sm; __syncthreads();
  for (int off = 64; off >= 8; off >>= 1){ if (t < off) red[t] += red[t + off]; __syncthreads(); }
  if (t < 8) ss[t] = red[t] + 1e-16f;
  __syncthreads();
  float acc = 0.f;
  for (int c0 = 0; c0 < tot; c0 += 128){
    int ce = min(128, tot - c0);
    for (int i = t; i < ce*8; i += 128){
      int le = i >> 3, hh = i & 7;
      int e = c0 + le;
      int s = (e < deg) ? csrc[beg + e] : n;
      if (hh == 0) esrc[le] = s;
      alpha[le][hh] = __expf(lrelu(a_s[s*8 + hh] + adn[hh]) - ms[hh]) / ss[hh];
    }
    __syncthreads();
    for (int i = 0; i < ce; i++){
      const float* row = xh + (size_t)esrc[i]*1024;
      #pragma unroll
      for (int h = 0; h < 8; h++) acc += alpha[i][h]*row[h*128 + t];
    }
    __syncthreads();
  }
  hout[(size_t)n*128 + t] = acc*0.125f + bias[t];
}

// ---------------- pooling + head ----------------
__global__ void k_gate_logit(const float* __restrict__ h, const float* __restrict__ w,
                             const float* __restrict__ b, float* __restrict__ logit){
  int n = blockIdx.x, l = threadIdx.x;
  float p = h[(size_t)n*128 + l]*w[l] + h[(size_t)n*128 + 64 + l]*w[64 + l];
  #pragma unroll
  for (int off = 32; off > 0; off >>= 1) p += __shfl_down(p, off);
  if (l == 0) logit[n] = p + b[0];
}

__global__ void k_pool(const float* __restrict__ h, const float* __restrict__ logit,
                       const int* __restrict__ gptr, float* __restrict__ pooled){
  int g = blockIdx.x, t = threadIdx.x;
  int beg = gptr[g], end = gptr[g+1];
  __shared__ float red[128];
  __shared__ float m_sh, s_sh;
  float mx = -1e30f;
  for (int i = beg + t; i < end; i += 128) mx = fmaxf(mx, logit[i]);
  red[t] = mx; __syncthreads();
  for (int off = 64; off > 0; off >>= 1){ if (t < off) red[t] = fmaxf(red[t], red[t + off]); __syncthreads(); }
  if (t == 0) m_sh = red[0];
  __syncthreads();
  float sm = 0.f;
  for (int i = beg + t; i < end; i += 128) sm += __expf(logit[i] - m_sh);
  red[t] = sm; __syncthreads();
  for (int off = 64; off > 0; off >>= 1){ if (t < off) red[t] += red[t + off]; __syncthreads(); }
  if (t == 0) s_sh = red[0] + 1e-16f;
  __syncthreads();
  float acc = 0.f;
  for (int i = beg; i < end; i++){
    float w = __expf(logit[i] - m_sh) / s_sh;
    acc += w * h[(size_t)i*128 + t];
  }
  pooled[g*128 + t] = acc;
}

__global__ void k_fc1(const float* __restrict__ pooled, const float* __restrict__ w,
                      const float* __restrict__ b, float* __restrict__ out){
  int g = blockIdx.x, t = threadIdx.x;
  __shared__ float row[128];
  row[t] = pooled[g*128 + t];
  __syncthreads();
  float acc = b[t];
  for (int k = 0; k < 128; k++) acc += row[k]*w[k*128 + t];
  out[g*128 + t] = fmaxf(acc, 0.f);
}

__global__ void k_fc2(const float* __restrict__ hid, const float* __restrict__ w,
                      const float* __restrict__ b, float* __restrict__ out){
  int g = blockIdx.x, t = threadIdx.x;
  __shared__ float r0[128], r1[128];
  float v = hid[g*128 + t];
  r0[t] = v*w[t*2 + 0]; r1[t] = v*w[t*2 + 1];
  __syncthreads();
  for (int off = 64; off > 0; off >>= 1){
    if (t < off){ r0[t] += r0[t + off]; r1[t] += r1[t + off]; }
    __syncthreads();
  }
  if (t == 0){ out[g*2 + 0] = r0[0] + b[0]; out[g*2 + 1] = r1[0] + b[1]; }
}

extern "C" void kernel_launch(void* const* d_in, const int* in_sizes, int n_in,
                              void* d_out, int out_size, void* d_ws, size_t ws_size,
                              hipStream_t stream) {
  // ---- inputs (setup_inputs dict order) ----
  const float* x        = (const float*)d_in[0];
  const int*   ei       = (const int*)  d_in[1];
  const int*   batch    = (const int*)  d_in[2];
  const float* gw1[4] = {(const float*)d_in[3],  (const float*)d_in[7],  (const float*)d_in[11], (const float*)d_in[15]};
  const float* gb1[4] = {(const float*)d_in[4],  (const float*)d_in[8],  (const float*)d_in[12], (const float*)d_in[16]};
  const float* gw2[4] = {(const float*)d_in[5],  (const float*)d_in[9],  (const float*)d_in[13], (const float*)d_in[17]};
  const float* gb2[4] = {(const float*)d_in[6],  (const float*)d_in[10], (const float*)d_in[14], (const float*)d_in[18]};
  const float* bng[5] = {(const float*)d_in[19], (const float*)d_in[21], (const float*)d_in[23], (const float*)d_in[25], (const float*)d_in[27]};
  const float* bnb[5] = {(const float*)d_in[20], (const float*)d_in[22], (const float*)d_in[24], (const float*)d_in[26], (const float*)d_in[28]};
  const float* gat_w    = (const float*)d_in[29];
  const float* gat_asrc = (const float*)d_in[30];
  const float* gat_adst = (const float*)d_in[31];
  const float* gat_bias = (const float*)d_in[32];
  const float* gate_w   = (const float*)d_in[33];
  const float* gate_b   = (const float*)d_in[34];
  const float* fc1_w    = (const float*)d_in[35];
  const float* fc1_b    = (const float*)d_in[36];
  const float* fc2_w    = (const float*)d_in[37];
  const float* fc2_b    = (const float*)d_in[38];
  const int* src = ei;
  const int* dst = ei + NE;

  // ---- workspace arena ----
  char* wsb = (char*)d_ws;
  size_t off = 0;
  auto take = [&](size_t bytes) -> void* {
    void* p = wsb + off;
    off = (off + bytes + 255) & ~(size_t)255;
    return p;
  };
  float*  hA     = (float*) take((size_t)NN*512*4);
  float*  zb     = (float*) take((size_t)NN*1024*4);   // z (<=512) | hid (<=512); together = xh [N,1024]
  float*  hid    = zb + (size_t)NN*512;
  double* stats  = (double*)take(1024*8);
  float*  scale  = (float*) take(512*4);
  float*  shiftb = (float*) take(512*4);
  float*  a_s    = (float*) take((size_t)NN*8*4);
  float*  a_d    = (float*) take((size_t)NN*8*4);
  float*  logit  = (float*) take((size_t)NN*4);
  float*  pooled = (float*) take((size_t)NG*128*4);
  float*  fchid  = (float*) take((size_t)NG*128*4);
  int*    deg    = (int*)   take((size_t)NN*4);
  int*    rowptr = (int*)   take((size_t)(NN+1)*4);
  int*    cnt    = (int*)   take((size_t)NN*4);
  int*    csrc   = (int*)   take((size_t)NE*4);
  int*    gdeg   = (int*)   take((size_t)NG*4);
  int*    gptr   = (int*)   take((size_t)(NG+1)*4);
  (void)ws_size; (void)n_in; (void)in_sizes; (void)out_size;

  // ---- CSR by dst + graph segments ----
  hipMemsetAsync(deg,  0, (size_t)NN*4, stream);
  hipMemsetAsync(cnt,  0, (size_t)NN*4, stream);
  hipMemsetAsync(gdeg, 0, (size_t)NG*4, stream);
  k_hist<<<(NE+255)/256, 256, 0, stream>>>(dst, NE, deg);
  k_scan<<<1, 1024, 0, stream>>>(deg, rowptr, NN);
  k_fill<<<(NE+255)/256, 256, 0, stream>>>(src, dst, rowptr, cnt, csrc);
  k_hist<<<(NN+255)/256, 256, 0, stream>>>(batch, NN, gdeg);
  k_scan<<<1, 1024, 0, stream>>>(gdeg, gptr, NG);

  const int GRID_M = (NN + 63) / 64;

  auto bn = [&](float* h, int d, const float* g, const float* b){
    hipMemsetAsync(stats, 0, (size_t)2*d*8, stream);
    k_bn_stats<<<(NN+63)/64, 256, 0, stream>>>(h, NN, d, stats);
    k_bn_finalize<<<(d+255)/256, 256, 0, stream>>>(stats, g, b, scale, shiftb, d);
    int total = NN*d;
    k_bn_relu<<<(total+255)/256, 256, 0, stream>>>(h, total, d-1, scale, shiftb);
  };

  auto gin = [&](const float* hin, int Din, int Dh, int Dout, int li){
    k_gin_agg<<<NN, (Din == 128 ? 128 : 256), 0, stream>>>(hin, rowptr, csrc, zb, Din);
    k_gemm<1><<<dim3(Dh/64, GRID_M), 256, 0, stream>>>(zb, gw1[li], gb1[li], hid, NN, Dh, Din);
    k_gemm<0><<<dim3(Dout/64, GRID_M), 256, 0, stream>>>(hid, gw2[li], gb2[li], hA, NN, Dout, Dh);
    bn(hA, Dout, bng[li], bnb[li]);
  };

  // ---- 4 GIN layers (+BN+ReLU) ----
  gin(x,  128, 128, 128, 0);
  gin(hA, 128, 256, 256, 1);
  gin(hA, 256, 512, 512, 2);
  gin(hA, 512, 256, 256, 3);

  // ---- GAT ----
  k_gemm<0><<<dim3(1024/64, GRID_M), 256, 0, stream>>>(hA, gat_w, nullptr, zb, NN, 1024, 256);
  k_gat_scores<<<NN, 64, 0, stream>>>(zb, gat_asrc, gat_adst, a_s, a_d);
  k_gat_node<<<NN, 128, 0, stream>>>(zb, a_s, a_d, rowptr, csrc, gat_bias, hA);
  bn(hA, 128, bng[4], bnb[4]);

  // ---- global attention pooling + MLP head ----
  k_gate_logit<<<NN, 64, 0, stream>>>(hA, gate_w, gate_b, logit);
  k_pool<<<NG, 128, 0, stream>>>(hA, logit, gptr, pooled);
  k_fc1<<<NG, 128, 0, stream>>>(pooled, fc1_w, fc1_b, fchid);
  k_fc2<<<NG, 128, 0, stream>>>(fchid, fc2_w, fc2_b, (float*)d_out);
}

// Round 2
// 818.501 us; speedup vs baseline: 1.7669x; 1.7669x over previous
//
#include <hip/hip_runtime.h>
#include <hip/hip_bf16.h>
#include <math.h>

#define NN 20000
#define NE 320000
#define NG 128

using bf16x8 = __attribute__((ext_vector_type(8))) short;
using f32x4  = __attribute__((ext_vector_type(4))) float;

static __device__ __forceinline__ float lrelu(float v){ return v > 0.f ? v : 0.2f*v; }
static __device__ __forceinline__ float b2f(unsigned short u){ unsigned int v = ((unsigned int)u) << 16; return __uint_as_float(v); }
static __device__ __forceinline__ unsigned short f2b(float f){
  unsigned int x = __float_as_uint(f);
  unsigned int r = x + 0x7fffu + ((x >> 16) & 1u);
  return (unsigned short)(r >> 16);
}

// ---------------- CSR build ----------------
__global__ void k_hist(const int* __restrict__ idx, int n, int* __restrict__ cnt){
  int i = blockIdx.x*blockDim.x + threadIdx.x;
  if (i < n) atomicAdd(&cnt[idx[i]], 1);
}

__global__ void k_scan(const int* __restrict__ deg, int* __restrict__ ptr, int n){
  __shared__ int tmp[1024];
  __shared__ int carry;
  int t = threadIdx.x;
  if (t == 0){ carry = 0; ptr[0] = 0; }
  __syncthreads();
  for (int c0 = 0; c0 < n; c0 += 1024){
    int v = (c0 + t < n) ? deg[c0 + t] : 0;
    tmp[t] = v; __syncthreads();
    for (int off = 1; off < 1024; off <<= 1){
      int u = (t >= off) ? tmp[t - off] : 0;
      __syncthreads();
      tmp[t] += u;
      __syncthreads();
    }
    if (c0 + t < n) ptr[c0 + t + 1] = carry + tmp[t];
    __syncthreads();
    if (t == 0) carry += tmp[1023];
    __syncthreads();
  }
}

__global__ void k_fill(const int* __restrict__ src, const int* __restrict__ dst,
                       const int* __restrict__ ptr, int* __restrict__ cnt,
                       int* __restrict__ csrc){
  int e = blockIdx.x*blockDim.x + threadIdx.x;
  if (e < NE){
    int d = dst[e];
    int p = atomicAdd(&cnt[d], 1);
    csrc[ptr[d] + p] = src[e];
  }
}

// ---------------- weight prep: fp32 [K][Nn] -> bf16 [Nn][K] ----------------
__global__ void k_wtrans(const float* __restrict__ W, unsigned short* __restrict__ Wt, int K, int Nn){
  int n = blockIdx.x;
  for (int k = threadIdx.x; k < K; k += blockDim.x)
    Wt[(size_t)n*K + k] = f2b(W[(size_t)k*Nn + n]);
}

__global__ void k_f2b(const float* __restrict__ x, unsigned int* __restrict__ out, int n2){
  int i = blockIdx.x*blockDim.x + threadIdx.x;
  if (i < n2){
    unsigned int lo = f2b(x[2*i]);
    unsigned int hi = f2b(x[2*i + 1]);
    out[i] = lo | (hi << 16);
  }
}

// ---------------- GIN aggregation (bf16 in/out, fp32 accumulate) ----------------
// block = DU threads (DU = D/2, uint lanes). z[n] = h[n] + sum_{in} h[src]
__global__ void k_gin_agg16(const unsigned int* __restrict__ h, const int* __restrict__ ptr,
                            const int* __restrict__ csrc, unsigned int* __restrict__ z, int DU){
  int n = blockIdx.x;
  int t = threadIdx.x, B = blockDim.x;
  int beg = ptr[n], deg = ptr[n+1] - beg;
  __shared__ int es[256];
  unsigned int self = h[(size_t)n*DU + t];
  float a0 = b2f(self & 0xffff), a1 = b2f(self >> 16);
  for (int c0 = 0; c0 < deg; c0 += 256){
    int ce = min(256, deg - c0);
    for (int i = t; i < ce; i += B) es[i] = csrc[beg + c0 + i];
    __syncthreads();
    for (int i = 0; i < ce; i++){
      unsigned int v = h[(size_t)es[i]*DU + t];
      a0 += b2f(v & 0xffff);
      a1 += b2f(v >> 16);
    }
    __syncthreads();
  }
  z[(size_t)n*DU + t] = (unsigned int)f2b(a0) | ((unsigned int)f2b(a1) << 16);
}

// ---------------- bf16 MFMA GEMM: C = act(A @ Bt^T + bias) ----------------
// A [M][K] bf16 row-major, Bt [Nn][K] bf16 row-major (i.e. B transposed).
// 128x128 tile, BK=32, 4 waves (2x2), each wave 64x64 via 4x4 x mfma_16x16x32.
#define LDAP 40
template<int ACT, int OBF>
__global__ __launch_bounds__(256)
void k_gemm_mfma(const unsigned short* __restrict__ A, const unsigned short* __restrict__ Bt,
                 const float* __restrict__ bias, float* __restrict__ C,
                 unsigned short* __restrict__ Cb, int M, int Nn, int K){
  __shared__ unsigned short As[128*LDAP];
  __shared__ unsigned short Bs[128*LDAP];
  const int bm = blockIdx.y*128, bn = blockIdx.x*128;
  const int tid = threadIdx.x;
  const int lane = tid & 63;
  const int wave = tid >> 6;
  const int wm = (wave >> 1)*64, wn = (wave & 1)*64;
  const int lr = lane & 15, lq = lane >> 4;

  f32x4 acc[4][4];
  #pragma unroll
  for (int i = 0; i < 4; i++)
    #pragma unroll
    for (int j = 0; j < 4; j++) acc[i][j] = (f32x4){0.f,0.f,0.f,0.f};

  const int r0 = tid >> 2, q0 = tid & 3;          // chunk 0: rows 0..63
  const int r1 = r0 + 64;                          // chunk 1: rows 64..127
  const uint4 zero4 = {0,0,0,0};

  for (int k0 = 0; k0 < K; k0 += 32){
    // stage A (guard M) and Bt (Nn multiple of 128, no guard)
    {
      int gm0 = bm + r0, gm1 = bm + r1;
      uint4 va0 = (gm0 < M) ? *(const uint4*)&A[(size_t)gm0*K + k0 + q0*8] : zero4;
      uint4 va1 = (gm1 < M) ? *(const uint4*)&A[(size_t)gm1*K + k0 + q0*8] : zero4;
      uint4 vb0 = *(const uint4*)&Bt[(size_t)(bn + r0)*K + k0 + q0*8];
      uint4 vb1 = *(const uint4*)&Bt[(size_t)(bn + r1)*K + k0 + q0*8];
      *(uint4*)&As[r0*LDAP + q0*8] = va0;
      *(uint4*)&As[r1*LDAP + q0*8] = va1;
      *(uint4*)&Bs[r0*LDAP + q0*8] = vb0;
      *(uint4*)&Bs[r1*LDAP + q0*8] = vb1;
    }
    __syncthreads();
    bf16x8 af[4], bf[4];
    #pragma unroll
    for (int mi = 0; mi < 4; mi++)
      af[mi] = *(const bf16x8*)&As[(wm + mi*16 + lr)*LDAP + lq*8];
    #pragma unroll
    for (int ni = 0; ni < 4; ni++)
      bf[ni] = *(const bf16x8*)&Bs[(wn + ni*16 + lr)*LDAP + lq*8];
    #pragma unroll
    for (int mi = 0; mi < 4; mi++)
      #pragma unroll
      for (int ni = 0; ni < 4; ni++)
        acc[mi][ni] = __builtin_amdgcn_mfma_f32_16x16x32_bf16(af[mi], bf[ni], acc[mi][ni], 0, 0, 0);
    __syncthreads();
  }

  // epilogue: D row=(lane>>4)*4+j, col=lane&15
  #pragma unroll
  for (int mi = 0; mi < 4; mi++){
    #pragma unroll
    for (int j = 0; j < 4; j++){
      int gm = bm + wm + mi*16 + lq*4 + j;
      if (gm < M){
        #pragma unroll
        for (int ni = 0; ni < 4; ni++){
          int gn = bn + wn + ni*16 + lr;
          float v = acc[mi][ni][j] + (bias ? bias[gn] : 0.f);
          if (ACT) v = fmaxf(v, 0.f);
          if (OBF) Cb[(size_t)gm*Nn + gn] = f2b(v);
          else     C [(size_t)gm*Nn + gn] = v;
        }
      }
    }
  }
}

// ---------------- BatchNorm ----------------
__global__ void k_bn_stats(const float* __restrict__ h, int n, int d, double* __restrict__ stats){
  int r0 = blockIdx.x*64;
  int rend = min(n, r0 + 64);
  for (int f = threadIdx.x; f < d; f += blockDim.x){
    float s = 0.f, q = 0.f;
    for (int r = r0; r < rend; r++){ float v = h[(size_t)r*d + f]; s += v; q += v*v; }
    atomicAdd(&stats[f], (double)s);
    atomicAdd(&stats[d + f], (double)q);
  }
}

__global__ void k_bn_finalize(const double* __restrict__ stats, const float* __restrict__ g,
                              const float* __restrict__ b, float* __restrict__ scale,
                              float* __restrict__ shift, int d){
  int f = blockIdx.x*blockDim.x + threadIdx.x;
  if (f >= d) return;
  double inv = 1.0 / (double)NN;
  double mu  = stats[f]*inv;
  double var = stats[d + f]*inv - mu*mu;
  if (var < 0.0) var = 0.0;
  float sc = g[f] * rsqrtf((float)var + 1e-5f);
  scale[f] = sc;
  shift[f] = b[f] - (float)mu*sc;
}

// float4; writes fp32 in place + bf16 copy
__global__ void k_bn_relu4(float* __restrict__ h, unsigned short* __restrict__ hb, int total4, int dmask,
                           const float* __restrict__ scale, const float* __restrict__ shift){
  int i = blockIdx.x*blockDim.x + threadIdx.x;
  if (i >= total4) return;
  int i4 = i*4;
  float4 v = *(float4*)&h[i4];
  int f = i4 & dmask;
  v.x = fmaxf(v.x*scale[f]   + shift[f],   0.f);
  v.y = fmaxf(v.y*scale[f+1] + shift[f+1], 0.f);
  v.z = fmaxf(v.z*scale[f+2] + shift[f+2], 0.f);
  v.w = fmaxf(v.w*scale[f+3] + shift[f+3], 0.f);
  *(float4*)&h[i4] = v;
  uint2 p;
  p.x = (unsigned int)f2b(v.x) | ((unsigned int)f2b(v.y) << 16);
  p.y = (unsigned int)f2b(v.z) | ((unsigned int)f2b(v.w) << 16);
  *(uint2*)&hb[i4] = p;
}

// ---------------- GAT ----------------
// xh bf16 [N][1024]; per node: a_s[h] = <xh[n,h,:], asrc[h,:]>, a_d likewise
__global__ void k_gat_scores16(const unsigned int* __restrict__ xhU, const float* __restrict__ asrc,
                               const float* __restrict__ adst, float* __restrict__ a_s,
                               float* __restrict__ a_d){
  int n = blockIdx.x, l = threadIdx.x;   // 64 threads
  const unsigned int* row = xhU + (size_t)n*512;
  const float2* as2 = (const float2*)asrc;
  const float2* ad2 = (const float2*)adst;
  for (int hd = 0; hd < 8; hd++){
    unsigned int u = row[hd*64 + l];
    float x0 = b2f(u & 0xffff), x1 = b2f(u >> 16);
    float2 a = as2[hd*64 + l];
    float2 d = ad2[hd*64 + l];
    float ps = x0*a.x + x1*a.y;
    float pd = x0*d.x + x1*d.y;
    #pragma unroll
    for (int off = 32; off > 0; off >>= 1){ ps += __shfl_down(ps, off); pd += __shfl_down(pd, off); }
    if (l == 0){ a_s[n*8 + hd] = ps; a_d[n*8 + hd] = pd; }
  }
}

// 128 threads; thread t: head h=t>>4, owns 8 cols c0=(t&15)*8 .. +7 (one uint4/edge)
__global__ __launch_bounds__(128)
void k_gat_node16(const unsigned short* __restrict__ xh, const float* __restrict__ a_s,
                  const float* __restrict__ a_d, const int* __restrict__ ptr,
                  const int* __restrict__ csrc, const float* __restrict__ bias,
                  float* __restrict__ hout){
  int n = blockIdx.x, t = threadIdx.x;
  int beg = ptr[n], deg = ptr[n+1] - beg;
  int tot = deg + 1;                         // + self-loop
  __shared__ float alpha_s[128][8];
  __shared__ int esrc[128];
  __shared__ float red[128];
  __shared__ float ms[8], ss[8], adn[8];
  __shared__ float partial[8][128];
  if (t < 8) adn[t] = a_d[n*8 + t];
  __syncthreads();
  int h16 = t >> 4, s16 = t & 15;
  // pass 1: max
  float mx = -1e30f;
  for (int e = s16; e < tot; e += 16){
    int s = (e < deg) ? csrc[beg + e] : n;
    mx = fmaxf(mx, lrelu(a_s[s*8 + h16] + adn[h16]));
  }
  red[t] = mx; __syncthreads();
  #pragma unroll
  for (int off = 8; off >= 1; off >>= 1){
    if (s16 < off) red[t] = fmaxf(red[t], red[t + off]);
    __syncthreads();
  }
  if (s16 == 0) ms[h16] = red[t];
  __syncthreads();
  // pass 2: sum
  float sm = 0.f;
  for (int e = s16; e < tot; e += 16){
    int s = (e < deg) ? csrc[beg + e] : n;
    sm += __expf(lrelu(a_s[s*8 + h16] + adn[h16]) - ms[h16]);
  }
  red[t] = sm; __syncthreads();
  #pragma unroll
  for (int off = 8; off >= 1; off >>= 1){
    if (s16 < off) red[t] += red[t + off];
    __syncthreads();
  }
  if (s16 == 0) ss[h16] = red[t] + 1e-16f;
  __syncthreads();
  // pass 3: weighted aggregate
  float acc[8] = {0.f,0.f,0.f,0.f,0.f,0.f,0.f,0.f};
  for (int ch = 0; ch < tot; ch += 128){
    int ce = min(128, tot - ch);
    for (int i = t; i < ce*8; i += 128){
      int le = i >> 3, hh = i & 7;
      int s = (ch + le < deg) ? csrc[beg + ch + le] : n;
      if (hh == 0) esrc[le] = s;
      alpha_s[le][hh] = __expf(lrelu(a_s[s*8 + hh] + adn[hh]) - ms[hh]) / ss[hh];
    }
    __syncthreads();
    for (int i = 0; i < ce; i++){
      const uint4* row = (const uint4*)(xh + (size_t)esrc[i]*1024);
      uint4 v = row[t];
      float a = alpha_s[i][t >> 4];
      acc[0] += a*b2f(v.x & 0xffff); acc[1] += a*b2f(v.x >> 16);
      acc[2] += a*b2f(v.y & 0xffff); acc[3] += a*b2f(v.y >> 16);
      acc[4] += a*b2f(v.z & 0xffff); acc[5] += a*b2f(v.z >> 16);
      acc[6] += a*b2f(v.w & 0xffff); acc[7] += a*b2f(v.w >> 16);
    }
    __syncthreads();
  }
  int c0 = (t & 15)*8;
  #pragma unroll
  for (int j = 0; j < 8; j++) partial[t >> 4][c0 + j] = acc[j];
  __syncthreads();
  float s = 0.f;
  #pragma unroll
  for (int hh = 0; hh < 8; hh++) s += partial[hh][t];
  hout[(size_t)n*128 + t] = s*0.125f + bias[t];
}

// ---------------- pooling + head ----------------
__global__ void k_gate_logit(const float* __restrict__ h, const float* __restrict__ w,
                             const float* __restrict__ b, float* __restrict__ logit){
  int n = blockIdx.x, l = threadIdx.x;
  float p = h[(size_t)n*128 + l]*w[l] + h[(size_t)n*128 + 64 + l]*w[64 + l];
  #pragma unroll
  for (int off = 32; off > 0; off >>= 1) p += __shfl_down(p, off);
  if (l == 0) logit[n] = p + b[0];
}

__global__ void k_pool(const float* __restrict__ h, const float* __restrict__ logit,
                       const int* __restrict__ gptr, float* __restrict__ pooled){
  int g = blockIdx.x, t = threadIdx.x;
  int beg = gptr[g], end = gptr[g+1];
  __shared__ float red[128];
  __shared__ float m_sh, s_sh;
  float mx = -1e30f;
  for (int i = beg + t; i < end; i += 128) mx = fmaxf(mx, logit[i]);
  red[t] = mx; __syncthreads();
  for (int off = 64; off > 0; off >>= 1){ if (t < off) red[t] = fmaxf(red[t], red[t + off]); __syncthreads(); }
  if (t == 0) m_sh = red[0];
  __syncthreads();
  float sm = 0.f;
  for (int i = beg + t; i < end; i += 128) sm += __expf(logit[i] - m_sh);
  red[t] = sm; __syncthreads();
  for (int off = 64; off > 0; off >>= 1){ if (t < off) red[t] += red[t + off]; __syncthreads(); }
  if (t == 0) s_sh = red[0] + 1e-16f;
  __syncthreads();
  float acc = 0.f;
  for (int i = beg; i < end; i++){
    float w = __expf(logit[i] - m_sh) / s_sh;
    acc += w * h[(size_t)i*128 + t];
  }
  pooled[g*128 + t] = acc;
}

__global__ void k_fc1(const float* __restrict__ pooled, const float* __restrict__ w,
                      const float* __restrict__ b, float* __restrict__ out){
  int g = blockIdx.x, t = threadIdx.x;
  __shared__ float row[128];
  row[t] = pooled[g*128 + t];
  __syncthreads();
  float acc = b[t];
  for (int k = 0; k < 128; k++) acc += row[k]*w[k*128 + t];
  out[g*128 + t] = fmaxf(acc, 0.f);
}

__global__ void k_fc2(const float* __restrict__ hid, const float* __restrict__ w,
                      const float* __restrict__ b, float* __restrict__ out){
  int g = blockIdx.x, t = threadIdx.x;
  __shared__ float r0[128], r1[128];
  float v = hid[g*128 + t];
  r0[t] = v*w[t*2 + 0]; r1[t] = v*w[t*2 + 1];
  __syncthreads();
  for (int off = 64; off > 0; off >>= 1){
    if (t < off){ r0[t] += r0[t + off]; r1[t] += r1[t + off]; }
    __syncthreads();
  }
  if (t == 0){ out[g*2 + 0] = r0[0] + b[0]; out[g*2 + 1] = r1[0] + b[1]; }
}

extern "C" void kernel_launch(void* const* d_in, const int* in_sizes, int n_in,
                              void* d_out, int out_size, void* d_ws, size_t ws_size,
                              hipStream_t stream) {
  const float* x        = (const float*)d_in[0];
  const int*   ei       = (const int*)  d_in[1];
  const int*   batch    = (const int*)  d_in[2];
  const float* gw1[4] = {(const float*)d_in[3],  (const float*)d_in[7],  (const float*)d_in[11], (const float*)d_in[15]};
  const float* gb1[4] = {(const float*)d_in[4],  (const float*)d_in[8],  (const float*)d_in[12], (const float*)d_in[16]};
  const float* gw2[4] = {(const float*)d_in[5],  (const float*)d_in[9],  (const float*)d_in[13], (const float*)d_in[17]};
  const float* gb2[4] = {(const float*)d_in[6],  (const float*)d_in[10], (const float*)d_in[14], (const float*)d_in[18]};
  const float* bng[5] = {(const float*)d_in[19], (const float*)d_in[21], (const float*)d_in[23], (const float*)d_in[25], (const float*)d_in[27]};
  const float* bnb[5] = {(const float*)d_in[20], (const float*)d_in[22], (const float*)d_in[24], (const float*)d_in[26], (const float*)d_in[28]};
  const float* gat_w    = (const float*)d_in[29];
  const float* gat_asrc = (const float*)d_in[30];
  const float* gat_adst = (const float*)d_in[31];
  const float* gat_bias = (const float*)d_in[32];
  const float* gate_w   = (const float*)d_in[33];
  const float* gate_b   = (const float*)d_in[34];
  const float* fc1_w    = (const float*)d_in[35];
  const float* fc1_b    = (const float*)d_in[36];
  const float* fc2_w    = (const float*)d_in[37];
  const float* fc2_b    = (const float*)d_in[38];
  const int* src = ei;
  const int* dst = ei + NE;

  char* wsb = (char*)d_ws;
  size_t off = 0;
  auto take = [&](size_t bytes) -> void* {
    void* p = wsb + off;
    off = (off + bytes + 255) & ~(size_t)255;
    return p;
  };
  float*          hA    = (float*)         take((size_t)NN*512*4);
  unsigned short* hb    = (unsigned short*)take((size_t)NN*512*2);
  unsigned short* zh    = (unsigned short*)take((size_t)NN*1024*2);  // z16 | hid16, contiguous = xh16
  unsigned short* z16   = zh;
  unsigned short* hid16 = zh + (size_t)NN*512;
  unsigned short* xh16  = zh;
  unsigned short* xb    = (unsigned short*)take((size_t)NN*128*2);
  unsigned short* wt    = (unsigned short*)take((size_t)1000000*2);
  double* stats  = (double*)take(1024*8);
  float*  scale  = (float*) take(512*4);
  float*  shiftb = (float*) take(512*4);
  float*  a_s    = (float*) take((size_t)NN*8*4);
  float*  a_d    = (float*) take((size_t)NN*8*4);
  float*  logit  = (float*) take((size_t)NN*4);
  float*  pooled = (float*) take((size_t)NG*128*4);
  float*  fchid  = (float*) take((size_t)NG*128*4);
  int*    deg    = (int*)   take((size_t)NN*4);
  int*    rowptr = (int*)   take((size_t)(NN+1)*4);
  int*    cnt    = (int*)   take((size_t)NN*4);
  int*    csrc   = (int*)   take((size_t)NE*4);
  int*    gdeg   = (int*)   take((size_t)NG*4);
  int*    gptr   = (int*)   take((size_t)(NG+1)*4);
  (void)ws_size; (void)n_in; (void)in_sizes; (void)out_size;

  // weight arena offsets (bf16, transposed [Nn][K])
  unsigned short* wt_g1w1 = wt;              // 128x128
  unsigned short* wt_g1w2 = wt_g1w1 + 128*128;
  unsigned short* wt_g2w1 = wt_g1w2 + 128*128;   // [256][128]
  unsigned short* wt_g2w2 = wt_g2w1 + 256*128;   // [256][256]
  unsigned short* wt_g3w1 = wt_g2w2 + 256*256;   // [512][256]
  unsigned short* wt_g3w2 = wt_g3w1 + 512*256;   // [512][512]
  unsigned short* wt_g4w1 = wt_g3w2 + 512*512;   // [256][512]
  unsigned short* wt_g4w2 = wt_g4w1 + 256*512;   // [256][256]
  unsigned short* wt_gat  = wt_g4w2 + 256*256;   // [1024][256]

  // ---- CSR + graph segments ----
  hipMemsetAsync(deg,  0, (size_t)NN*4, stream);
  hipMemsetAsync(cnt,  0, (size_t)NN*4, stream);
  hipMemsetAsync(gdeg, 0, (size_t)NG*4, stream);
  k_hist<<<(NE+255)/256, 256, 0, stream>>>(dst, NE, deg);
  k_scan<<<1, 1024, 0, stream>>>(deg, rowptr, NN);
  k_fill<<<(NE+255)/256, 256, 0, stream>>>(src, dst, rowptr, cnt, csrc);
  k_hist<<<(NN+255)/256, 256, 0, stream>>>(batch, NN, gdeg);
  k_scan<<<1, 1024, 0, stream>>>(gdeg, gptr, NG);

  // ---- weight prep ----
  k_wtrans<<<128,  256, 0, stream>>>(gw1[0], wt_g1w1, 128, 128);
  k_wtrans<<<128,  256, 0, stream>>>(gw2[0], wt_g1w2, 128, 128);
  k_wtrans<<<256,  256, 0, stream>>>(gw1[1], wt_g2w1, 128, 256);
  k_wtrans<<<256,  256, 0, stream>>>(gw2[1], wt_g2w2, 256, 256);
  k_wtrans<<<512,  256, 0, stream>>>(gw1[2], wt_g3w1, 256, 512);
  k_wtrans<<<512,  256, 0, stream>>>(gw2[2], wt_g3w2, 512, 512);
  k_wtrans<<<256,  256, 0, stream>>>(gw1[3], wt_g4w1, 512, 256);
  k_wtrans<<<256,  256, 0, stream>>>(gw2[3], wt_g4w2, 256, 256);
  k_wtrans<<<1024, 256, 0, stream>>>(gat_w,  wt_gat,  256, 1024);
  k_f2b<<<(NN*64 + 255)/256, 256, 0, stream>>>(x, (unsigned int*)xb, NN*64);

  const int GM = (NN + 127) / 128;

  auto bn = [&](float* h, int d, const float* g, const float* b){
    hipMemsetAsync(stats, 0, (size_t)2*d*8, stream);
    k_bn_stats<<<(NN+63)/64, 256, 0, stream>>>(h, NN, d, stats);
    k_bn_finalize<<<(d+255)/256, 256, 0, stream>>>(stats, g, b, scale, shiftb, d);
    int total4 = NN*d/4;
    k_bn_relu4<<<(total4+255)/256, 256, 0, stream>>>(h, hb, total4, d-1, scale, shiftb);
  };

  auto gin = [&](const unsigned short* hin, int Din, int Dh, int Dout, int li,
                 const unsigned short* w1t, const unsigned short* w2t){
    k_gin_agg16<<<NN, Din/2, 0, stream>>>((const unsigned int*)hin, rowptr, csrc, (unsigned int*)z16, Din/2);
    k_gemm_mfma<1,1><<<dim3(Dh/128, GM), 256, 0, stream>>>(z16, w1t, gb1[li], nullptr, hid16, NN, Dh, Din);
    k_gemm_mfma<0,0><<<dim3(Dout/128, GM), 256, 0, stream>>>(hid16, w2t, gb2[li], hA, nullptr, NN, Dout, Dh);
    bn(hA, Dout, bng[li], bnb[li]);
  };

  gin(xb, 128, 128, 128, 0, wt_g1w1, wt_g1w2);
  gin(hb, 128, 256, 256, 1, wt_g2w1, wt_g2w2);
  gin(hb, 256, 512, 512, 2, wt_g3w1, wt_g3w2);
  gin(hb, 512, 256, 256, 3, wt_g4w1, wt_g4w2);

  // ---- GAT ----
  k_gemm_mfma<0,1><<<dim3(1024/128, GM), 256, 0, stream>>>(hb, wt_gat, nullptr, nullptr, xh16, NN, 1024, 256);
  k_gat_scores16<<<NN, 64, 0, stream>>>((const unsigned int*)xh16, gat_asrc, gat_adst, a_s, a_d);
  k_gat_node16<<<NN, 128, 0, stream>>>(xh16, a_s, a_d, rowptr, csrc, gat_bias, hA);
  bn(hA, 128, bng[4], bnb[4]);

  // ---- pooling + head ----
  k_gate_logit<<<NN, 64, 0, stream>>>(hA, gate_w, gate_b, logit);
  k_pool<<<NG, 128, 0, stream>>>(hA, logit, gptr, pooled);
  k_fc1<<<NG, 128, 0, stream>>>(pooled, fc1_w, fc1_b, fchid);
  k_fc2<<<NG, 128, 0, stream>>>(fchid, fc2_w, fc2_b, (float*)d_out);
}

// Round 3
// 708.066 us; speedup vs baseline: 2.0425x; 1.1560x over previous
//
#include <hip/hip_runtime.h>
#include <hip/hip_bf16.h>
#include <math.h>

#define NN 20000
#define NE 320000
#define NG 128

using bf16x8 = __attribute__((ext_vector_type(8))) short;
using f32x4  = __attribute__((ext_vector_type(4))) float;

static __device__ __forceinline__ float lrelu(float v){ return v > 0.f ? v : 0.2f*v; }
static __device__ __forceinline__ float b2f(unsigned short u){ unsigned int v = ((unsigned int)u) << 16; return __uint_as_float(v); }
static __device__ __forceinline__ unsigned short f2b(float f){
  unsigned int x = __float_as_uint(f);
  unsigned int r = x + 0x7fffu + ((x >> 16) & 1u);
  return (unsigned short)(r >> 16);
}

// ---------------- CSR build ----------------
__global__ void k_hist(const int* __restrict__ idx, int n, int* __restrict__ cnt){
  int i = blockIdx.x*blockDim.x + threadIdx.x;
  if (i < n) atomicAdd(&cnt[idx[i]], 1);
}

__global__ void k_scan(const int* __restrict__ deg, int* __restrict__ ptr, int n){
  __shared__ int tmp[1024];
  __shared__ int carry;
  int t = threadIdx.x;
  if (t == 0){ carry = 0; ptr[0] = 0; }
  __syncthreads();
  for (int c0 = 0; c0 < n; c0 += 1024){
    int v = (c0 + t < n) ? deg[c0 + t] : 0;
    tmp[t] = v; __syncthreads();
    for (int off = 1; off < 1024; off <<= 1){
      int u = (t >= off) ? tmp[t - off] : 0;
      __syncthreads();
      tmp[t] += u;
      __syncthreads();
    }
    if (c0 + t < n) ptr[c0 + t + 1] = carry + tmp[t];
    __syncthreads();
    if (t == 0) carry += tmp[1023];
    __syncthreads();
  }
}

__global__ void k_fill(const int* __restrict__ src, const int* __restrict__ dst,
                       const int* __restrict__ ptr, int* __restrict__ cnt,
                       int* __restrict__ csrc){
  int e = blockIdx.x*blockDim.x + threadIdx.x;
  if (e < NE){
    int d = dst[e];
    int p = atomicAdd(&cnt[d], 1);
    csrc[ptr[d] + p] = src[e];
  }
}

// ---------------- weight prep: fp32 [K][Nn] -> bf16 [Nn][K] ----------------
__global__ void k_wtrans(const float* __restrict__ W, unsigned short* __restrict__ Wt, int K, int Nn){
  int n = blockIdx.x;
  for (int k = threadIdx.x; k < K; k += blockDim.x)
    Wt[(size_t)n*K + k] = f2b(W[(size_t)k*Nn + n]);
}

__global__ void k_f2b(const float* __restrict__ x, unsigned int* __restrict__ out, int n2){
  int i = blockIdx.x*blockDim.x + threadIdx.x;
  if (i < n2){
    unsigned int lo = f2b(x[2*i]);
    unsigned int hi = f2b(x[2*i + 1]);
    out[i] = lo | (hi << 16);
  }
}

// ---------------- GIN aggregation (bf16 in/out, fp32 accumulate), unroll-4 ----------------
// BR=1: z = relu(agg + bias)   (post-w1 aggregation for gin4)
template<int BR>
__global__ void k_gin_agg16(const unsigned int* __restrict__ h, const int* __restrict__ ptr,
                            const int* __restrict__ csrc, unsigned int* __restrict__ z, int DU,
                            const float* __restrict__ bias){
  int n = blockIdx.x;
  int t = threadIdx.x, B = blockDim.x;
  int beg = ptr[n], deg = ptr[n+1] - beg;
  __shared__ int es[256];
  unsigned int self = h[(size_t)n*DU + t];
  float a0 = b2f(self & 0xffff), a1 = b2f(self >> 16);
  for (int c0 = 0; c0 < deg; c0 += 256){
    int ce = min(256, deg - c0);
    for (int i = t; i < ce; i += B) es[i] = csrc[beg + c0 + i];
    __syncthreads();
    int i = 0;
    for (; i + 4 <= ce; i += 4){
      unsigned int v0 = h[(size_t)es[i]*DU + t];
      unsigned int v1 = h[(size_t)es[i+1]*DU + t];
      unsigned int v2 = h[(size_t)es[i+2]*DU + t];
      unsigned int v3 = h[(size_t)es[i+3]*DU + t];
      a0 += b2f(v0 & 0xffff) + b2f(v1 & 0xffff) + b2f(v2 & 0xffff) + b2f(v3 & 0xffff);
      a1 += b2f(v0 >> 16)    + b2f(v1 >> 16)    + b2f(v2 >> 16)    + b2f(v3 >> 16);
    }
    for (; i < ce; i++){
      unsigned int v = h[(size_t)es[i]*DU + t];
      a0 += b2f(v & 0xffff); a1 += b2f(v >> 16);
    }
    __syncthreads();
  }
  if (BR){
    a0 = fmaxf(a0 + bias[2*t],     0.f);
    a1 = fmaxf(a1 + bias[2*t + 1], 0.f);
  }
  z[(size_t)n*DU + t] = (unsigned int)f2b(a0) | ((unsigned int)f2b(a1) << 16);
}

// ---------------- bf16 MFMA GEMM: C = act(A @ Bt^T + bias), optional fused BN stats ----------------
#define LDAP 40
template<int ACT, int OBF, int STATS>
__global__ __launch_bounds__(256)
void k_gemm_mfma(const unsigned short* __restrict__ A, const unsigned short* __restrict__ Bt,
                 const float* __restrict__ bias, float* __restrict__ C,
                 unsigned short* __restrict__ Cb, double* __restrict__ stats,
                 int M, int Nn, int K){
  __shared__ unsigned short As[128*LDAP];
  __shared__ unsigned short Bs[128*LDAP];
  const int bm = blockIdx.y*128, bn = blockIdx.x*128;
  const int tid = threadIdx.x;
  const int lane = tid & 63;
  const int wave = tid >> 6;
  const int wm = (wave >> 1)*64, wn = (wave & 1)*64;
  const int lr = lane & 15, lq = lane >> 4;

  f32x4 acc[4][4];
  #pragma unroll
  for (int i = 0; i < 4; i++)
    #pragma unroll
    for (int j = 0; j < 4; j++) acc[i][j] = (f32x4){0.f,0.f,0.f,0.f};

  const int r0 = tid >> 2, q0 = tid & 3;
  const int r1 = r0 + 64;
  const uint4 zero4 = {0,0,0,0};

  for (int k0 = 0; k0 < K; k0 += 32){
    {
      int gm0 = bm + r0, gm1 = bm + r1;
      uint4 va0 = (gm0 < M) ? *(const uint4*)&A[(size_t)gm0*K + k0 + q0*8] : zero4;
      uint4 va1 = (gm1 < M) ? *(const uint4*)&A[(size_t)gm1*K + k0 + q0*8] : zero4;
      uint4 vb0 = *(const uint4*)&Bt[(size_t)(bn + r0)*K + k0 + q0*8];
      uint4 vb1 = *(const uint4*)&Bt[(size_t)(bn + r1)*K + k0 + q0*8];
      *(uint4*)&As[r0*LDAP + q0*8] = va0;
      *(uint4*)&As[r1*LDAP + q0*8] = va1;
      *(uint4*)&Bs[r0*LDAP + q0*8] = vb0;
      *(uint4*)&Bs[r1*LDAP + q0*8] = vb1;
    }
    __syncthreads();
    bf16x8 af[4], bf[4];
    #pragma unroll
    for (int mi = 0; mi < 4; mi++)
      af[mi] = *(const bf16x8*)&As[(wm + mi*16 + lr)*LDAP + lq*8];
    #pragma unroll
    for (int ni = 0; ni < 4; ni++)
      bf[ni] = *(const bf16x8*)&Bs[(wn + ni*16 + lr)*LDAP + lq*8];
    #pragma unroll
    for (int mi = 0; mi < 4; mi++)
      #pragma unroll
      for (int ni = 0; ni < 4; ni++)
        acc[mi][ni] = __builtin_amdgcn_mfma_f32_16x16x32_bf16(af[mi], bf[ni], acc[mi][ni], 0, 0, 0);
    __syncthreads();
  }

  float cs[4] = {0.f,0.f,0.f,0.f}, cq[4] = {0.f,0.f,0.f,0.f};
  #pragma unroll
  for (int mi = 0; mi < 4; mi++){
    #pragma unroll
    for (int j = 0; j < 4; j++){
      int gm = bm + wm + mi*16 + lq*4 + j;
      if (gm < M){
        #pragma unroll
        for (int ni = 0; ni < 4; ni++){
          int gn = bn + wn + ni*16 + lr;
          float v = acc[mi][ni][j] + (bias ? bias[gn] : 0.f);
          if (ACT) v = fmaxf(v, 0.f);
          if (OBF) Cb[(size_t)gm*Nn + gn] = f2b(v);
          else     C [(size_t)gm*Nn + gn] = v;
          if (STATS){ cs[ni] += v; cq[ni] += v*v; }
        }
      }
    }
  }
  if (STATS){
    #pragma unroll
    for (int ni = 0; ni < 4; ni++){
      float s = cs[ni], q = cq[ni];
      s += __shfl_xor(s, 16); s += __shfl_xor(s, 32);
      q += __shfl_xor(q, 16); q += __shfl_xor(q, 32);
      if (lane < 16){
        int gn = bn + wn + ni*16 + lr;
        atomicAdd(&stats[gn],      (double)s);
        atomicAdd(&stats[Nn + gn], (double)q);
      }
    }
  }
}

// ---------------- BatchNorm ----------------
__global__ void k_bn_stats(const float* __restrict__ h, int n, int d, double* __restrict__ stats){
  int r0 = blockIdx.x*64;
  int rend = min(n, r0 + 64);
  for (int f = threadIdx.x; f < d; f += blockDim.x){
    float s = 0.f, q = 0.f;
    for (int r = r0; r < rend; r++){ float v = h[(size_t)r*d + f]; s += v; q += v*v; }
    atomicAdd(&stats[f], (double)s);
    atomicAdd(&stats[d + f], (double)q);
  }
}

__global__ void k_bn_finalize(const double* __restrict__ stats, const float* __restrict__ g,
                              const float* __restrict__ b, float* __restrict__ scale,
                              float* __restrict__ shift, int d){
  int f = blockIdx.x*blockDim.x + threadIdx.x;
  if (f >= d) return;
  double inv = 1.0 / (double)NN;
  double mu  = stats[f]*inv;
  double var = stats[d + f]*inv - mu*mu;
  if (var < 0.0) var = 0.0;
  float sc = g[f] * rsqrtf((float)var + 1e-5f);
  scale[f] = sc;
  shift[f] = b[f] - (float)mu*sc;
}

// reads fp32, writes bf16 only
__global__ void k_bn_relu_b16(const float* __restrict__ h, unsigned short* __restrict__ hb, int total4, int dmask,
                              const float* __restrict__ scale, const float* __restrict__ shift){
  int i = blockIdx.x*blockDim.x + threadIdx.x;
  if (i >= total4) return;
  int i4 = i*4;
  float4 v = *(const float4*)&h[i4];
  int f = i4 & dmask;
  v.x = fmaxf(v.x*scale[f]   + shift[f],   0.f);
  v.y = fmaxf(v.y*scale[f+1] + shift[f+1], 0.f);
  v.z = fmaxf(v.z*scale[f+2] + shift[f+2], 0.f);
  v.w = fmaxf(v.w*scale[f+3] + shift[f+3], 0.f);
  uint2 p;
  p.x = (unsigned int)f2b(v.x) | ((unsigned int)f2b(v.y) << 16);
  p.y = (unsigned int)f2b(v.z) | ((unsigned int)f2b(v.w) << 16);
  *(uint2*)&hb[i4] = p;
}

// ---------------- GAT ----------------
__global__ void k_gat_scores16(const unsigned int* __restrict__ xhU, const float* __restrict__ asrc,
                               const float* __restrict__ adst, float* __restrict__ a_s,
                               float* __restrict__ a_d){
  int n = blockIdx.x, l = threadIdx.x;   // 64 threads
  const unsigned int* row = xhU + (size_t)n*512;
  const float2* as2 = (const float2*)asrc;
  const float2* ad2 = (const float2*)adst;
  for (int hd = 0; hd < 8; hd++){
    unsigned int u = row[hd*64 + l];
    float x0 = b2f(u & 0xffff), x1 = b2f(u >> 16);
    float2 a = as2[hd*64 + l];
    float2 d = ad2[hd*64 + l];
    float ps = x0*a.x + x1*a.y;
    float pd = x0*d.x + x1*d.y;
    #pragma unroll
    for (int off = 32; off > 0; off >>= 1){ ps += __shfl_down(ps, off); pd += __shfl_down(pd, off); }
    if (l == 0){ a_s[n*8 + hd] = ps; a_d[n*8 + hd] = pd; }
  }
}

// 256 threads: 2 independent edge streams; single-pass score LDS cache (fast path tot<=256)
__global__ __launch_bounds__(256)
void k_gat_node256(const unsigned short* __restrict__ xh, const float* __restrict__ a_s,
                   const float* __restrict__ a_d, const int* __restrict__ ptr,
                   const int* __restrict__ csrc, const float* __restrict__ bias,
                   float* __restrict__ hout){
  int n = blockIdx.x, t = threadIdx.x;
  int beg = ptr[n], deg = ptr[n+1] - beg;
  int tot = deg + 1;                          // + self-loop
  __shared__ float elv[256][9];               // padded: scores then exp values
  __shared__ int esrc[256];
  __shared__ float red[256];
  __shared__ float ms[8], ssinv[8], adn[8];
  __shared__ float partial[16][132];
  if (t < 8) adn[t] = a_d[n*8 + t];
  __syncthreads();
  int head = t >> 5, slot = t & 31;
  int sub = t >> 7, tt = t & 127;
  int h16 = tt >> 4;
  float acc[8] = {0.f,0.f,0.f,0.f,0.f,0.f,0.f,0.f};

  if (tot <= 256){
    for (int i = t; i < tot; i += 256) esrc[i] = (i < deg) ? csrc[beg + i] : n;
    __syncthreads();
    for (int i = t; i < tot*8; i += 256){
      int le = i >> 3, hh = i & 7;
      elv[le][hh] = lrelu(a_s[esrc[le]*8 + hh] + adn[hh]);
    }
    __syncthreads();
    float mx = -1e30f;
    for (int e = slot; e < tot; e += 32) mx = fmaxf(mx, elv[e][head]);
    red[t] = mx; __syncthreads();
    #pragma unroll
    for (int off = 16; off >= 1; off >>= 1){
      if (slot < off) red[t] = fmaxf(red[t], red[t + off]);
      __syncthreads();
    }
    if (slot == 0) ms[head] = red[t];
    __syncthreads();
    float sm = 0.f;
    for (int e = slot; e < tot; e += 32){
      float ex = __expf(elv[e][head] - ms[head]);
      elv[e][head] = ex;
      sm += ex;
    }
    red[t] = sm; __syncthreads();
    #pragma unroll
    for (int off = 16; off >= 1; off >>= 1){
      if (slot < off) red[t] += red[t + off];
      __syncthreads();
    }
    if (slot == 0) ssinv[head] = 1.f / (red[t] + 1e-16f);
    __syncthreads();
    // gather
    int lo = sub*128, hi = min(tot, lo + 128);
    float si = ssinv[h16];
    int i = lo;
    for (; i + 2 <= hi; i += 2){
      const uint4* r0 = (const uint4*)(xh + (size_t)esrc[i]*1024);
      const uint4* r1 = (const uint4*)(xh + (size_t)esrc[i+1]*1024);
      uint4 v0 = r0[tt], v1 = r1[tt];
      float a0 = elv[i][h16]*si, a1 = elv[i+1][h16]*si;
      acc[0] += a0*b2f(v0.x & 0xffff) + a1*b2f(v1.x & 0xffff);
      acc[1] += a0*b2f(v0.x >> 16)    + a1*b2f(v1.x >> 16);
      acc[2] += a0*b2f(v0.y & 0xffff) + a1*b2f(v1.y & 0xffff);
      acc[3] += a0*b2f(v0.y >> 16)    + a1*b2f(v1.y >> 16);
      acc[4] += a0*b2f(v0.z & 0xffff) + a1*b2f(v1.z & 0xffff);
      acc[5] += a0*b2f(v0.z >> 16)    + a1*b2f(v1.z >> 16);
      acc[6] += a0*b2f(v0.w & 0xffff) + a1*b2f(v1.w & 0xffff);
      acc[7] += a0*b2f(v0.w >> 16)    + a1*b2f(v1.w >> 16);
    }
    for (; i < hi; i++){
      const uint4* r0 = (const uint4*)(xh + (size_t)esrc[i]*1024);
      uint4 v0 = r0[tt];
      float a0 = elv[i][h16]*si;
      acc[0] += a0*b2f(v0.x & 0xffff); acc[1] += a0*b2f(v0.x >> 16);
      acc[2] += a0*b2f(v0.y & 0xffff); acc[3] += a0*b2f(v0.y >> 16);
      acc[4] += a0*b2f(v0.z & 0xffff); acc[5] += a0*b2f(v0.z >> 16);
      acc[6] += a0*b2f(v0.w & 0xffff); acc[7] += a0*b2f(v0.w >> 16);
    }
    __syncthreads();
  } else {
    // fallback: global two-pass softmax, chunked gather
    float mx = -1e30f;
    for (int e = slot; e < tot; e += 32){
      int s = (e < deg) ? csrc[beg + e] : n;
      mx = fmaxf(mx, lrelu(a_s[s*8 + head] + adn[head]));
    }
    red[t] = mx; __syncthreads();
    #pragma unroll
    for (int off = 16; off >= 1; off >>= 1){
      if (slot < off) red[t] = fmaxf(red[t], red[t + off]);
      __syncthreads();
    }
    if (slot == 0) ms[head] = red[t];
    __syncthreads();
    float sm = 0.f;
    for (int e = slot; e < tot; e += 32){
      int s = (e < deg) ? csrc[beg + e] : n;
      sm += __expf(lrelu(a_s[s*8 + head] + adn[head]) - ms[head]);
    }
    red[t] = sm; __syncthreads();
    #pragma unroll
    for (int off = 16; off >= 1; off >>= 1){
      if (slot < off) red[t] += red[t + off];
      __syncthreads();
    }
    if (slot == 0) ssinv[head] = 1.f / (red[t] + 1e-16f);
    __syncthreads();
    float si = ssinv[h16];
    for (int ch = 0; ch < tot; ch += 256){
      int ce = min(256, tot - ch);
      for (int i = t; i < ce*8; i += 256){
        int le = i >> 3, hh = i & 7;
        int s = (ch + le < deg) ? csrc[beg + ch + le] : n;
        if (hh == 0) esrc[le] = s;
        elv[le][hh] = __expf(lrelu(a_s[s*8 + hh] + adn[hh]) - ms[hh]);
      }
      __syncthreads();
      int lo = sub*128, hi = min(ce, lo + 128);
      for (int i = lo; i < hi; i++){
        const uint4* r0 = (const uint4*)(xh + (size_t)esrc[i]*1024);
        uint4 v0 = r0[tt];
        float a0 = elv[i][h16]*si;
        acc[0] += a0*b2f(v0.x & 0xffff); acc[1] += a0*b2f(v0.x >> 16);
        acc[2] += a0*b2f(v0.y & 0xffff); acc[3] += a0*b2f(v0.y >> 16);
        acc[4] += a0*b2f(v0.z & 0xffff); acc[5] += a0*b2f(v0.z >> 16);
        acc[6] += a0*b2f(v0.w & 0xffff); acc[7] += a0*b2f(v0.w >> 16);
      }
      __syncthreads();
    }
  }

  int c0 = (tt & 15)*8;
  #pragma unroll
  for (int j = 0; j < 8; j++) partial[sub*8 + h16][c0 + j] = acc[j];
  __syncthreads();
  if (t < 128){
    float s = 0.f;
    #pragma unroll
    for (int g = 0; g < 16; g++) s += partial[g][t];
    hout[(size_t)n*128 + t] = s*0.125f + bias[t];
  }
}

// ---------------- pooling + head (bf16 h) ----------------
__global__ void k_gate_logit16(const unsigned int* __restrict__ hU, const float* __restrict__ w,
                               const float* __restrict__ b, float* __restrict__ logit){
  int n = blockIdx.x, l = threadIdx.x;   // 64
  unsigned int u = hU[(size_t)n*64 + l];
  float p = b2f(u & 0xffff)*w[2*l] + b2f(u >> 16)*w[2*l + 1];
  #pragma unroll
  for (int off = 32; off > 0; off >>= 1) p += __shfl_down(p, off);
  if (l == 0) logit[n] = p + b[0];
}

__global__ void k_pool16(const unsigned short* __restrict__ h, const float* __restrict__ logit,
                         const int* __restrict__ gptr, float* __restrict__ pooled){
  int g = blockIdx.x, t = threadIdx.x;
  int beg = gptr[g], end = gptr[g+1];
  __shared__ float red[128];
  __shared__ float m_sh, s_sh;
  float mx = -1e30f;
  for (int i = beg + t; i < end; i += 128) mx = fmaxf(mx, logit[i]);
  red[t] = mx; __syncthreads();
  for (int off = 64; off > 0; off >>= 1){ if (t < off) red[t] = fmaxf(red[t], red[t + off]); __syncthreads(); }
  if (t == 0) m_sh = red[0];
  __syncthreads();
  float sm = 0.f;
  for (int i = beg + t; i < end; i += 128) sm += __expf(logit[i] - m_sh);
  red[t] = sm; __syncthreads();
  for (int off = 64; off > 0; off >>= 1){ if (t < off) red[t] += red[t + off]; __syncthreads(); }
  if (t == 0) s_sh = red[0] + 1e-16f;
  __syncthreads();
  float acc = 0.f;
  for (int i = beg; i < end; i++){
    float w = __expf(logit[i] - m_sh) / s_sh;
    acc += w * b2f(h[(size_t)i*128 + t]);
  }
  pooled[g*128 + t] = acc;
}

__global__ void k_fc1(const float* __restrict__ pooled, const float* __restrict__ w,
                      const float* __restrict__ b, float* __restrict__ out){
  int g = blockIdx.x, t = threadIdx.x;
  __shared__ float row[128];
  row[t] = pooled[g*128 + t];
  __syncthreads();
  float acc = b[t];
  for (int k = 0; k < 128; k++) acc += row[k]*w[k*128 + t];
  out[g*128 + t] = fmaxf(acc, 0.f);
}

__global__ void k_fc2(const float* __restrict__ hid, const float* __restrict__ w,
                      const float* __restrict__ b, float* __restrict__ out){
  int g = blockIdx.x, t = threadIdx.x;
  __shared__ float r0[128], r1[128];
  float v = hid[g*128 + t];
  r0[t] = v*w[t*2 + 0]; r1[t] = v*w[t*2 + 1];
  __syncthreads();
  for (int off = 64; off > 0; off >>= 1){
    if (t < off){ r0[t] += r0[t + off]; r1[t] += r1[t + off]; }
    __syncthreads();
  }
  if (t == 0){ out[g*2 + 0] = r0[0] + b[0]; out[g*2 + 1] = r1[0] + b[1]; }
}

extern "C" void kernel_launch(void* const* d_in, const int* in_sizes, int n_in,
                              void* d_out, int out_size, void* d_ws, size_t ws_size,
                              hipStream_t stream) {
  const float* x        = (const float*)d_in[0];
  const int*   ei       = (const int*)  d_in[1];
  const int*   batch    = (const int*)  d_in[2];
  const float* gw1[4] = {(const float*)d_in[3],  (const float*)d_in[7],  (const float*)d_in[11], (const float*)d_in[15]};
  const float* gb1[4] = {(const float*)d_in[4],  (const float*)d_in[8],  (const float*)d_in[12], (const float*)d_in[16]};
  const float* gw2[4] = {(const float*)d_in[5],  (const float*)d_in[9],  (const float*)d_in[13], (const float*)d_in[17]};
  const float* gb2[4] = {(const float*)d_in[6],  (const float*)d_in[10], (const float*)d_in[14], (const float*)d_in[18]};
  const float* bng[5] = {(const float*)d_in[19], (const float*)d_in[21], (const float*)d_in[23], (const float*)d_in[25], (const float*)d_in[27]};
  const float* bnb[5] = {(const float*)d_in[20], (const float*)d_in[22], (const float*)d_in[24], (const float*)d_in[26], (const float*)d_in[28]};
  const float* gat_w    = (const float*)d_in[29];
  const float* gat_asrc = (const float*)d_in[30];
  const float* gat_adst = (const float*)d_in[31];
  const float* gat_bias = (const float*)d_in[32];
  const float* gate_w   = (const float*)d_in[33];
  const float* gate_b   = (const float*)d_in[34];
  const float* fc1_w    = (const float*)d_in[35];
  const float* fc1_b    = (const float*)d_in[36];
  const float* fc2_w    = (const float*)d_in[37];
  const float* fc2_b    = (const float*)d_in[38];
  const int* src = ei;
  const int* dst = ei + NE;

  char* wsb = (char*)d_ws;
  size_t off = 0;
  auto take = [&](size_t bytes) -> void* {
    void* p = wsb + off;
    off = (off + bytes + 255) & ~(size_t)255;
    return p;
  };
  float*          hA    = (float*)         take((size_t)NN*512*4);
  unsigned short* hb    = (unsigned short*)take((size_t)NN*512*2);
  unsigned short* zh    = (unsigned short*)take((size_t)NN*1024*2);  // z16 | hid16; contiguous = xh16
  unsigned short* z16   = zh;
  unsigned short* hid16 = zh + (size_t)NN*512;
  unsigned short* xh16  = zh;
  unsigned short* xb    = (unsigned short*)take((size_t)NN*128*2);
  unsigned short* wt    = (unsigned short*)take((size_t)1000000*2);
  double* stats  = (double*)take(1024*8);
  float*  scale  = (float*) take(512*4);
  float*  shiftb = (float*) take(512*4);
  float*  a_s    = (float*) take((size_t)NN*8*4);
  float*  a_d    = (float*) take((size_t)NN*8*4);
  float*  logit  = (float*) take((size_t)NN*4);
  float*  pooled = (float*) take((size_t)NG*128*4);
  float*  fchid  = (float*) take((size_t)NG*128*4);
  int*    deg    = (int*)   take((size_t)NN*4);
  int*    rowptr = (int*)   take((size_t)(NN+1)*4);
  int*    cnt    = (int*)   take((size_t)NN*4);
  int*    csrc   = (int*)   take((size_t)NE*4);
  int*    gdeg   = (int*)   take((size_t)NG*4);
  int*    gptr   = (int*)   take((size_t)(NG+1)*4);
  (void)ws_size; (void)n_in; (void)in_sizes; (void)out_size;

  unsigned short* wt_g1w1 = wt;
  unsigned short* wt_g1w2 = wt_g1w1 + 128*128;
  unsigned short* wt_g2w1 = wt_g1w2 + 128*128;
  unsigned short* wt_g2w2 = wt_g2w1 + 256*128;
  unsigned short* wt_g3w1 = wt_g2w2 + 256*256;
  unsigned short* wt_g3w2 = wt_g3w1 + 512*256;
  unsigned short* wt_g4w1 = wt_g3w2 + 512*512;
  unsigned short* wt_g4w2 = wt_g4w1 + 256*512;
  unsigned short* wt_gat  = wt_g4w2 + 256*256;

  // ---- CSR + graph segments ----
  hipMemsetAsync(deg,  0, (size_t)NN*4, stream);
  hipMemsetAsync(cnt,  0, (size_t)NN*4, stream);
  hipMemsetAsync(gdeg, 0, (size_t)NG*4, stream);
  k_hist<<<(NE+255)/256, 256, 0, stream>>>(dst, NE, deg);
  k_scan<<<1, 1024, 0, stream>>>(deg, rowptr, NN);
  k_fill<<<(NE+255)/256, 256, 0, stream>>>(src, dst, rowptr, cnt, csrc);
  k_hist<<<(NN+255)/256, 256, 0, stream>>>(batch, NN, gdeg);
  k_scan<<<1, 1024, 0, stream>>>(gdeg, gptr, NG);

  // ---- weight prep ----
  k_wtrans<<<128,  256, 0, stream>>>(gw1[0], wt_g1w1, 128, 128);
  k_wtrans<<<128,  256, 0, stream>>>(gw2[0], wt_g1w2, 128, 128);
  k_wtrans<<<256,  256, 0, stream>>>(gw1[1], wt_g2w1, 128, 256);
  k_wtrans<<<256,  256, 0, stream>>>(gw2[1], wt_g2w2, 256, 256);
  k_wtrans<<<512,  256, 0, stream>>>(gw1[2], wt_g3w1, 256, 512);
  k_wtrans<<<512,  256, 0, stream>>>(gw2[2], wt_g3w2, 512, 512);
  k_wtrans<<<256,  256, 0, stream>>>(gw1[3], wt_g4w1, 512, 256);
  k_wtrans<<<256,  256, 0, stream>>>(gw2[3], wt_g4w2, 256, 256);
  k_wtrans<<<1024, 256, 0, stream>>>(gat_w,  wt_gat,  256, 1024);
  k_f2b<<<(NN*64 + 255)/256, 256, 0, stream>>>(x, (unsigned int*)xb, NN*64);

  const int GM = (NN + 127) / 128;

  auto bnTail = [&](int d, const float* g, const float* b){
    k_bn_finalize<<<(d+255)/256, 256, 0, stream>>>(stats, g, b, scale, shiftb, d);
    int total4 = NN*d/4;
    k_bn_relu_b16<<<(total4+255)/256, 256, 0, stream>>>(hA, hb, total4, d-1, scale, shiftb);
  };

  // GIN layers 1-3: aggregate before w1 (Din <= Dh)
  auto ginPre = [&](const unsigned short* hin, int Din, int Dh, int Dout, int li,
                    const unsigned short* w1t, const unsigned short* w2t){
    k_gin_agg16<0><<<NN, Din/2, 0, stream>>>((const unsigned int*)hin, rowptr, csrc, (unsigned int*)z16, Din/2, nullptr);
    k_gemm_mfma<1,1,0><<<dim3(Dh/128, GM), 256, 0, stream>>>(z16, w1t, gb1[li], nullptr, hid16, nullptr, NN, Dh, Din);
    hipMemsetAsync(stats, 0, (size_t)2*Dout*8, stream);
    k_gemm_mfma<0,0,1><<<dim3(Dout/128, GM), 256, 0, stream>>>(hid16, w2t, gb2[li], hA, nullptr, stats, NN, Dout, Dh);
    bnTail(Dout, bng[li], bnb[li]);
  };

  ginPre(xb, 128, 128, 128, 0, wt_g1w1, wt_g1w2);
  ginPre(hb, 128, 256, 256, 1, wt_g2w1, wt_g2w2);
  ginPre(hb, 256, 512, 512, 2, wt_g3w1, wt_g3w2);

  // GIN4: aggregate AFTER w1 (512 -> 256): relu(h@w1 + A(h@w1) + b1)
  {
    k_gemm_mfma<0,1,0><<<dim3(256/128, GM), 256, 0, stream>>>(hb, wt_g4w1, nullptr, nullptr, hid16, nullptr, NN, 256, 512);
    k_gin_agg16<1><<<NN, 128, 0, stream>>>((const unsigned int*)hid16, rowptr, csrc, (unsigned int*)z16, 128, gb1[3]);
    hipMemsetAsync(stats, 0, (size_t)2*256*8, stream);
    k_gemm_mfma<0,0,1><<<dim3(256/128, GM), 256, 0, stream>>>(z16, wt_g4w2, gb2[3], hA, nullptr, stats, NN, 256, 256);
    bnTail(256, bng[3], bnb[3]);
  }

  // ---- GAT ----
  k_gemm_mfma<0,1,0><<<dim3(1024/128, GM), 256, 0, stream>>>(hb, wt_gat, nullptr, nullptr, xh16, nullptr, NN, 1024, 256);
  k_gat_scores16<<<NN, 64, 0, stream>>>((const unsigned int*)xh16, gat_asrc, gat_adst, a_s, a_d);
  k_gat_node256<<<NN, 256, 0, stream>>>(xh16, a_s, a_d, rowptr, csrc, gat_bias, hA);
  hipMemsetAsync(stats, 0, (size_t)2*128*8, stream);
  k_bn_stats<<<(NN+63)/64, 256, 0, stream>>>(hA, NN, 128, stats);
  bnTail(128, bng[4], bnb[4]);

  // ---- pooling + head ----
  k_gate_logit16<<<NN, 64, 0, stream>>>((const unsigned int*)hb, gate_w, gate_b, logit);
  k_pool16<<<NG, 128, 0, stream>>>(hb, logit, gptr, pooled);
  k_fc1<<<NG, 128, 0, stream>>>(pooled, fc1_w, fc1_b, fchid);
  k_fc2<<<NG, 128, 0, stream>>>(fchid, fc2_w, fc2_b, (float*)d_out);
}

// Round 4
// 640.569 us; speedup vs baseline: 2.2577x; 1.1054x over previous
//
#include <hip/hip_runtime.h>
#include <hip/hip_bf16.h>
#include <math.h>

#define NN 20000
#define NE 320000
#define NG 128

using bf16x8 = __attribute__((ext_vector_type(8))) short;
using f32x4  = __attribute__((ext_vector_type(4))) float;

static __device__ __forceinline__ float lrelu(float v){ return v > 0.f ? v : 0.2f*v; }
static __device__ __forceinline__ float b2f(unsigned short u){ unsigned int v = ((unsigned int)u) << 16; return __uint_as_float(v); }
static __device__ __forceinline__ unsigned short f2b(float f){
  unsigned int x = __float_as_uint(f);
  unsigned int r = x + 0x7fffu + ((x >> 16) & 1u);
  return (unsigned short)(r >> 16);
}
static __device__ __forceinline__ void gl16(const unsigned short* g, unsigned short* l){
  __builtin_amdgcn_global_load_lds((const __attribute__((address_space(1))) void*)g,
                                   (__attribute__((address_space(3))) void*)l, 16, 0, 0);
}

// ---------------- CSR build ----------------
__global__ void k_hist2(const int* __restrict__ dst, const int* __restrict__ batch,
                        int* __restrict__ deg, int* __restrict__ gdeg){
  int i = blockIdx.x*blockDim.x + threadIdx.x;
  if (i < NE) atomicAdd(&deg[dst[i]], 1);
  else if (i < NE + NN) atomicAdd(&gdeg[batch[i - NE]], 1);
}

static __device__ void scan_seq(const int* __restrict__ deg, int* __restrict__ ptr, int n){
  __shared__ int tmp[1024];
  __shared__ int carry;
  int t = threadIdx.x;
  if (t == 0){ carry = 0; ptr[0] = 0; }
  __syncthreads();
  for (int c0 = 0; c0 < n; c0 += 1024){
    int v = (c0 + t < n) ? deg[c0 + t] : 0;
    tmp[t] = v; __syncthreads();
    for (int off = 1; off < 1024; off <<= 1){
      int u = (t >= off) ? tmp[t - off] : 0;
      __syncthreads();
      tmp[t] += u;
      __syncthreads();
    }
    if (c0 + t < n) ptr[c0 + t + 1] = carry + tmp[t];
    __syncthreads();
    if (t == 0) carry += tmp[1023];
    __syncthreads();
  }
}

__global__ void k_scan2(const int* __restrict__ deg, int* __restrict__ rowptr,
                        const int* __restrict__ gdeg, int* __restrict__ gptr){
  if (blockIdx.x == 0) scan_seq(deg, rowptr, NN);
  else                 scan_seq(gdeg, gptr, NG);
}

__global__ void k_fill(const int* __restrict__ src, const int* __restrict__ dst,
                       const int* __restrict__ ptr, int* __restrict__ cnt,
                       int* __restrict__ csrc){
  int e = blockIdx.x*blockDim.x + threadIdx.x;
  if (e < NE){
    int d = dst[e];
    int p = atomicAdd(&cnt[d], 1);
    csrc[ptr[d] + p] = src[e];
  }
}

// ---------------- combined weight prep ----------------
struct WPrep {
  const float* W[9];
  unsigned short* Wt[9];
  int K[9];
  int Nn[9];
  int colStart[10];
  const float* x;
  unsigned int* xb;
};

__global__ void k_prep(WPrep P){
  int b = blockIdx.x;
  if (b < P.colStart[9]){
    int i = 0;
    while (i < 8 && b >= P.colStart[i+1]) i++;
    int n = b - P.colStart[i];
    const float* W = P.W[i];
    unsigned short* Wt = P.Wt[i];
    int K = P.K[i], Nn = P.Nn[i];
    for (int k = threadIdx.x; k < K; k += blockDim.x)
      Wt[(size_t)n*K + k] = f2b(W[(size_t)k*Nn + n]);
  } else {
    int idx = (b - P.colStart[9])*blockDim.x + threadIdx.x;
    if (idx < NN*64){
      unsigned int lo = f2b(P.x[2*idx]);
      unsigned int hi = f2b(P.x[2*idx + 1]);
      P.xb[idx] = lo | (hi << 16);
    }
  }
}

// ---------------- GIN aggregation (bf16 in/out, fp32 accumulate), unroll-4 ----------------
template<int BR>
__global__ void k_gin_agg16(const unsigned int* __restrict__ h, const int* __restrict__ ptr,
                            const int* __restrict__ csrc, unsigned int* __restrict__ z, int DU,
                            const float* __restrict__ bias){
  int n = blockIdx.x;
  int t = threadIdx.x, B = blockDim.x;
  int beg = ptr[n], deg = ptr[n+1] - beg;
  __shared__ int es[256];
  unsigned int self = h[(size_t)n*DU + t];
  float a0 = b2f(self & 0xffff), a1 = b2f(self >> 16);
  for (int c0 = 0; c0 < deg; c0 += 256){
    int ce = min(256, deg - c0);
    for (int i = t; i < ce; i += B) es[i] = csrc[beg + c0 + i];
    __syncthreads();
    int i = 0;
    for (; i + 4 <= ce; i += 4){
      unsigned int v0 = h[(size_t)es[i]*DU + t];
      unsigned int v1 = h[(size_t)es[i+1]*DU + t];
      unsigned int v2 = h[(size_t)es[i+2]*DU + t];
      unsigned int v3 = h[(size_t)es[i+3]*DU + t];
      a0 += b2f(v0 & 0xffff) + b2f(v1 & 0xffff) + b2f(v2 & 0xffff) + b2f(v3 & 0xffff);
      a1 += b2f(v0 >> 16)    + b2f(v1 >> 16)    + b2f(v2 >> 16)    + b2f(v3 >> 16);
    }
    for (; i < ce; i++){
      unsigned int v = h[(size_t)es[i]*DU + t];
      a0 += b2f(v & 0xffff); a1 += b2f(v >> 16);
    }
    __syncthreads();
  }
  if (BR){
    a0 = fmaxf(a0 + bias[2*t],     0.f);
    a1 = fmaxf(a1 + bias[2*t + 1], 0.f);
  }
  z[(size_t)n*DU + t] = (unsigned int)f2b(a0) | ((unsigned int)f2b(a1) << 16);
}

// ---------------- bf16 MFMA GEMM (global_load_lds staging) ----------------
// A [M][K] bf16, Bt [Nn][K] bf16. 128x128 tile, BK=32, 4 waves 2x2.
// OBF: write bf16; STATS: fused BN sum/sumsq; SCORES: fused GAT a_s/a_d (requires Nn=1024 head tiles)
template<int ACT, int OBF, int STATS, int SCORES>
__global__ __launch_bounds__(256)
void k_gemm_mfma(const unsigned short* __restrict__ A, const unsigned short* __restrict__ Bt,
                 const float* __restrict__ bias, float* __restrict__ C,
                 unsigned short* __restrict__ Cb, double* __restrict__ stats,
                 const float* __restrict__ asrc, const float* __restrict__ adst,
                 float* __restrict__ a_s, float* __restrict__ a_d,
                 int M, int Nn, int K){
  __shared__ unsigned short As[128*32];
  __shared__ unsigned short Bs[128*32];
  __shared__ float sS[SCORES ? 128 : 1];
  __shared__ float sD[SCORES ? 128 : 1];
  const int bm = blockIdx.y*128, bn = blockIdx.x*128;
  const int tid = threadIdx.x;
  const int lane = tid & 63;
  const int wave = tid >> 6;
  const int wm = (wave >> 1)*64, wn = (wave & 1)*64;
  const int lr = lane & 15, lq = lane >> 4;

  f32x4 acc[4][4];
  #pragma unroll
  for (int i = 0; i < 4; i++)
    #pragma unroll
    for (int j = 0; j < 4; j++) acc[i][j] = (f32x4){0.f,0.f,0.f,0.f};

  const int rowA = tid >> 2, q = tid & 3;       // rows 0..63, 16B quarter
  unsigned short* AsW = &As[(size_t)(wave*16)*32];
  unsigned short* BsW = &Bs[(size_t)(wave*16)*32];
  const int gmA0 = min(bm + rowA,      M-1);
  const int gmA1 = min(bm + rowA + 64, M-1);
  const unsigned short* pA0 = &A[(size_t)gmA0*K + q*8];
  const unsigned short* pA1 = &A[(size_t)gmA1*K + q*8];
  const unsigned short* pB0 = &Bt[(size_t)(bn + rowA)*K + q*8];
  const unsigned short* pB1 = &Bt[(size_t)(bn + rowA + 64)*K + q*8];

  for (int k0 = 0; k0 < K; k0 += 32){
    gl16(pA0 + k0, AsW);
    gl16(pA1 + k0, AsW + 64*32);
    gl16(pB0 + k0, BsW);
    gl16(pB1 + k0, BsW + 64*32);
    __syncthreads();
    bf16x8 af[4], bf[4];
    #pragma unroll
    for (int mi = 0; mi < 4; mi++)
      af[mi] = *(const bf16x8*)&As[(wm + mi*16 + lr)*32 + lq*8];
    #pragma unroll
    for (int ni = 0; ni < 4; ni++)
      bf[ni] = *(const bf16x8*)&Bs[(wn + ni*16 + lr)*32 + lq*8];
    #pragma unroll
    for (int mi = 0; mi < 4; mi++)
      #pragma unroll
      for (int ni = 0; ni < 4; ni++)
        acc[mi][ni] = __builtin_amdgcn_mfma_f32_16x16x32_bf16(af[mi], bf[ni], acc[mi][ni], 0, 0, 0);
    __syncthreads();
  }

  float cs[4] = {0.f,0.f,0.f,0.f}, cq[4] = {0.f,0.f,0.f,0.f};
  #pragma unroll
  for (int mi = 0; mi < 4; mi++){
    #pragma unroll
    for (int j = 0; j < 4; j++){
      int gm = bm + wm + mi*16 + lq*4 + j;
      if (gm < M){
        #pragma unroll
        for (int ni = 0; ni < 4; ni++){
          int gn = bn + wn + ni*16 + lr;
          float v = acc[mi][ni][j] + (bias ? bias[gn] : 0.f);
          if (ACT) v = fmaxf(v, 0.f);
          if (OBF) Cb[(size_t)gm*Nn + gn] = f2b(v);
          else     C [(size_t)gm*Nn + gn] = v;
          if (STATS){ cs[ni] += v; cq[ni] += v*v; }
        }
      }
    }
  }
  if (STATS){
    #pragma unroll
    for (int ni = 0; ni < 4; ni++){
      float s = cs[ni], qq = cq[ni];
      s += __shfl_xor(s, 16); s += __shfl_xor(s, 32);
      qq += __shfl_xor(qq, 16); qq += __shfl_xor(qq, 32);
      if (lane < 16){
        int gn = bn + wn + ni*16 + lr;
        atomicAdd(&stats[gn],      (double)s);
        atomicAdd(&stats[Nn + gn], (double)qq);
      }
    }
  }
  if (SCORES){
    const int hd = bn >> 7;
    float av[4], dv[4];
    #pragma unroll
    for (int ni = 0; ni < 4; ni++){
      int c = wn + ni*16 + lr;
      av[ni] = asrc[hd*128 + c];
      dv[ni] = adst[hd*128 + c];
    }
    float psS[4][4], psD[4][4];
    #pragma unroll
    for (int mi = 0; mi < 4; mi++)
      #pragma unroll
      for (int j = 0; j < 4; j++){
        float s = 0.f, d2 = 0.f;
        #pragma unroll
        for (int ni = 0; ni < 4; ni++){
          float v = acc[mi][ni][j];
          s  += v*av[ni];
          d2 += v*dv[ni];
        }
        #pragma unroll
        for (int o = 1; o < 16; o <<= 1){ s += __shfl_xor(s, o); d2 += __shfl_xor(d2, o); }
        psS[mi][j] = s; psD[mi][j] = d2;
      }
    if (wn == 0 && lr == 0){
      #pragma unroll
      for (int mi = 0; mi < 4; mi++)
        #pragma unroll
        for (int j = 0; j < 4; j++){
          int r = wm + mi*16 + lq*4 + j;
          sS[r] = psS[mi][j]; sD[r] = psD[mi][j];
        }
    }
    __syncthreads();
    if (wn != 0 && lr == 0){
      #pragma unroll
      for (int mi = 0; mi < 4; mi++)
        #pragma unroll
        for (int j = 0; j < 4; j++){
          int r = wm + mi*16 + lq*4 + j;
          sS[r] += psS[mi][j]; sD[r] += psD[mi][j];
        }
    }
    __syncthreads();
    if (tid < 128){
      int gm = bm + tid;
      if (gm < M){ a_s[gm*8 + hd] = sS[tid]; a_d[gm*8 + hd] = sD[tid]; }
    }
  }
}

// ---------------- BatchNorm (bf16 pre-BN input, finalize folded, optional gate fusion) ----------------
__global__ void k_bn_stats16(const unsigned short* __restrict__ h, int d, double* __restrict__ stats){
  int r0 = blockIdx.x*64;
  int rend = min(NN, r0 + 64);
  for (int f = threadIdx.x; f < d; f += blockDim.x){
    float s = 0.f, q = 0.f;
    for (int r = r0; r < rend; r++){ float v = b2f(h[(size_t)r*d + f]); s += v; q += v*v; }
    atomicAdd(&stats[f], (double)s);
    atomicAdd(&stats[d + f], (double)q);
  }
}

template<int GATE>
__global__ __launch_bounds__(256)
void k_bn_relu16(const unsigned short* __restrict__ hpre, unsigned short* __restrict__ hb,
                 int total8, int dmask, int d, const double* __restrict__ stats,
                 const float* __restrict__ g, const float* __restrict__ b,
                 const float* __restrict__ gatew, const float* __restrict__ gateb,
                 float* __restrict__ logit){
  __shared__ float scs[512], shs[512];
  for (int f = threadIdx.x; f < d; f += blockDim.x){
    double inv = 1.0 / (double)NN;
    double mu  = stats[f]*inv;
    double var = stats[d + f]*inv - mu*mu;
    if (var < 0.0) var = 0.0;
    float sc = g[f] * rsqrtf((float)var + 1e-5f);
    scs[f] = sc;
    shs[f] = b[f] - (float)mu*sc;
  }
  __syncthreads();
  int i = blockIdx.x*blockDim.x + threadIdx.x;
  if (i >= total8) return;
  int i8 = i*8;
  uint4 u = *(const uint4*)&hpre[i8];
  float v[8] = { b2f(u.x & 0xffff), b2f(u.x >> 16), b2f(u.y & 0xffff), b2f(u.y >> 16),
                 b2f(u.z & 0xffff), b2f(u.z >> 16), b2f(u.w & 0xffff), b2f(u.w >> 16) };
  int f0 = i8 & dmask;
  float gp = 0.f;
  #pragma unroll
  for (int j = 0; j < 8; j++){
    float y = fmaxf(v[j]*scs[f0 + j] + shs[f0 + j], 0.f);
    v[j] = y;
    if (GATE) gp += y*gatew[f0 + j];
  }
  uint4 p;
  p.x = (unsigned int)f2b(v[0]) | ((unsigned int)f2b(v[1]) << 16);
  p.y = (unsigned int)f2b(v[2]) | ((unsigned int)f2b(v[3]) << 16);
  p.z = (unsigned int)f2b(v[4]) | ((unsigned int)f2b(v[5]) << 16);
  p.w = (unsigned int)f2b(v[6]) | ((unsigned int)f2b(v[7]) << 16);
  *(uint4*)&hb[i8] = p;
  if (GATE){
    #pragma unroll
    for (int o = 1; o < 16; o <<= 1) gp += __shfl_xor(gp, o);
    if ((threadIdx.x & 15) == 0) logit[i >> 4] = gp + gateb[0];
  }
}

// ---------------- GAT node aggregate (writes bf16) ----------------
__global__ __launch_bounds__(256)
void k_gat_node256(const unsigned short* __restrict__ xh, const float* __restrict__ a_s,
                   const float* __restrict__ a_d, const int* __restrict__ ptr,
                   const int* __restrict__ csrc, const float* __restrict__ bias,
                   unsigned short* __restrict__ hout){
  int n = blockIdx.x, t = threadIdx.x;
  int beg = ptr[n], deg = ptr[n+1] - beg;
  int tot = deg + 1;
  __shared__ float elv[256][9];
  __shared__ int esrc[256];
  __shared__ float red[256];
  __shared__ float ms[8], ssinv[8], adn[8];
  __shared__ float partial[16][132];
  if (t < 8) adn[t] = a_d[n*8 + t];
  __syncthreads();
  int head = t >> 5, slot = t & 31;
  int sub = t >> 7, tt = t & 127;
  int h16 = tt >> 4;
  float acc[8] = {0.f,0.f,0.f,0.f,0.f,0.f,0.f,0.f};

  if (tot <= 256){
    for (int i = t; i < tot; i += 256) esrc[i] = (i < deg) ? csrc[beg + i] : n;
    __syncthreads();
    for (int i = t; i < tot*8; i += 256){
      int le = i >> 3, hh = i & 7;
      elv[le][hh] = lrelu(a_s[esrc[le]*8 + hh] + adn[hh]);
    }
    __syncthreads();
    float mx = -1e30f;
    for (int e = slot; e < tot; e += 32) mx = fmaxf(mx, elv[e][head]);
    red[t] = mx; __syncthreads();
    #pragma unroll
    for (int off = 16; off >= 1; off >>= 1){
      if (slot < off) red[t] = fmaxf(red[t], red[t + off]);
      __syncthreads();
    }
    if (slot == 0) ms[head] = red[t];
    __syncthreads();
    float sm = 0.f;
    for (int e = slot; e < tot; e += 32){
      float ex = __expf(elv[e][head] - ms[head]);
      elv[e][head] = ex;
      sm += ex;
    }
    red[t] = sm; __syncthreads();
    #pragma unroll
    for (int off = 16; off >= 1; off >>= 1){
      if (slot < off) red[t] += red[t + off];
      __syncthreads();
    }
    if (slot == 0) ssinv[head] = 1.f / (red[t] + 1e-16f);
    __syncthreads();
    int lo = sub*128, hi = min(tot, lo + 128);
    float si = ssinv[h16];
    int i = lo;
    for (; i + 2 <= hi; i += 2){
      const uint4* r0 = (const uint4*)(xh + (size_t)esrc[i]*1024);
      const uint4* r1 = (const uint4*)(xh + (size_t)esrc[i+1]*1024);
      uint4 v0 = r0[tt], v1 = r1[tt];
      float a0 = elv[i][h16]*si, a1 = elv[i+1][h16]*si;
      acc[0] += a0*b2f(v0.x & 0xffff) + a1*b2f(v1.x & 0xffff);
      acc[1] += a0*b2f(v0.x >> 16)    + a1*b2f(v1.x >> 16);
      acc[2] += a0*b2f(v0.y & 0xffff) + a1*b2f(v1.y & 0xffff);
      acc[3] += a0*b2f(v0.y >> 16)    + a1*b2f(v1.y >> 16);
      acc[4] += a0*b2f(v0.z & 0xffff) + a1*b2f(v1.z & 0xffff);
      acc[5] += a0*b2f(v0.z >> 16)    + a1*b2f(v1.z >> 16);
      acc[6] += a0*b2f(v0.w & 0xffff) + a1*b2f(v1.w & 0xffff);
      acc[7] += a0*b2f(v0.w >> 16)    + a1*b2f(v1.w >> 16);
    }
    for (; i < hi; i++){
      const uint4* r0 = (const uint4*)(xh + (size_t)esrc[i]*1024);
      uint4 v0 = r0[tt];
      float a0 = elv[i][h16]*si;
      acc[0] += a0*b2f(v0.x & 0xffff); acc[1] += a0*b2f(v0.x >> 16);
      acc[2] += a0*b2f(v0.y & 0xffff); acc[3] += a0*b2f(v0.y >> 16);
      acc[4] += a0*b2f(v0.z & 0xffff); acc[5] += a0*b2f(v0.z >> 16);
      acc[6] += a0*b2f(v0.w & 0xffff); acc[7] += a0*b2f(v0.w >> 16);
    }
    __syncthreads();
  } else {
    float mx = -1e30f;
    for (int e = slot; e < tot; e += 32){
      int s = (e < deg) ? csrc[beg + e] : n;
      mx = fmaxf(mx, lrelu(a_s[s*8 + head] + adn[head]));
    }
    red[t] = mx; __syncthreads();
    #pragma unroll
    for (int off = 16; off >= 1; off >>= 1){
      if (slot < off) red[t] = fmaxf(red[t], red[t + off]);
      __syncthreads();
    }
    if (slot == 0) ms[head] = red[t];
    __syncthreads();
    float sm = 0.f;
    for (int e = slot; e < tot; e += 32){
      int s = (e < deg) ? csrc[beg + e] : n;
      sm += __expf(lrelu(a_s[s*8 + head] + adn[head]) - ms[head]);
    }
    red[t] = sm; __syncthreads();
    #pragma unroll
    for (int off = 16; off >= 1; off >>= 1){
      if (slot < off) red[t] += red[t + off];
      __syncthreads();
    }
    if (slot == 0) ssinv[head] = 1.f / (red[t] + 1e-16f);
    __syncthreads();
    float si = ssinv[h16];
    for (int ch = 0; ch < tot; ch += 256){
      int ce = min(256, tot - ch);
      for (int i = t; i < ce*8; i += 256){
        int le = i >> 3, hh = i & 7;
        int s = (ch + le < deg) ? csrc[beg + ch + le] : n;
        if (hh == 0) esrc[le] = s;
        elv[le][hh] = __expf(lrelu(a_s[s*8 + hh] + adn[hh]) - ms[hh]);
      }
      __syncthreads();
      int lo = sub*128, hi = min(ce, lo + 128);
      for (int i = lo; i < hi; i++){
        const uint4* r0 = (const uint4*)(xh + (size_t)esrc[i]*1024);
        uint4 v0 = r0[tt];
        float a0 = elv[i][h16]*si;
        acc[0] += a0*b2f(v0.x & 0xffff); acc[1] += a0*b2f(v0.x >> 16);
        acc[2] += a0*b2f(v0.y & 0xffff); acc[3] += a0*b2f(v0.y >> 16);
        acc[4] += a0*b2f(v0.z & 0xffff); acc[5] += a0*b2f(v0.z >> 16);
        acc[6] += a0*b2f(v0.w & 0xffff); acc[7] += a0*b2f(v0.w >> 16);
      }
      __syncthreads();
    }
  }

  int c0 = (tt & 15)*8;
  #pragma unroll
  for (int j = 0; j < 8; j++) partial[sub*8 + h16][c0 + j] = acc[j];
  __syncthreads();
  if (t < 128){
    float s = 0.f;
    #pragma unroll
    for (int g = 0; g < 16; g++) s += partial[g][t];
    hout[(size_t)n*128 + t] = f2b(s*0.125f + bias[t]);
  }
}

// ---------------- pooling + fused head ----------------
__global__ void k_pool16(const unsigned short* __restrict__ h, const float* __restrict__ logit,
                         const int* __restrict__ gptr, float* __restrict__ pooled){
  int g = blockIdx.x, t = threadIdx.x;
  int beg = gptr[g], end = gptr[g+1];
  __shared__ float red[128];
  __shared__ float m_sh, s_sh;
  float mx = -1e30f;
  for (int i = beg + t; i < end; i += 128) mx = fmaxf(mx, logit[i]);
  red[t] = mx; __syncthreads();
  for (int off = 64; off > 0; off >>= 1){ if (t < off) red[t] = fmaxf(red[t], red[t + off]); __syncthreads(); }
  if (t == 0) m_sh = red[0];
  __syncthreads();
  float sm = 0.f;
  for (int i = beg + t; i < end; i += 128) sm += __expf(logit[i] - m_sh);
  red[t] = sm; __syncthreads();
  for (int off = 64; off > 0; off >>= 1){ if (t < off) red[t] += red[t + off]; __syncthreads(); }
  if (t == 0) s_sh = red[0] + 1e-16f;
  __syncthreads();
  float acc = 0.f;
  for (int i = beg; i < end; i++){
    float w = __expf(logit[i] - m_sh) / s_sh;
    acc += w * b2f(h[(size_t)i*128 + t]);
  }
  pooled[g*128 + t] = acc;
}

__global__ void k_head(const float* __restrict__ pooled,
                       const float* __restrict__ w1, const float* __restrict__ b1,
                       const float* __restrict__ w2, const float* __restrict__ b2,
                       float* __restrict__ out){
  int g = blockIdx.x, t = threadIdx.x;   // 128
  __shared__ float row[128];
  __shared__ float r0[128], r1[128];
  row[t] = pooled[g*128 + t];
  __syncthreads();
  float acc = b1[t];
  for (int k = 0; k < 128; k++) acc += row[k]*w1[k*128 + t];
  acc = fmaxf(acc, 0.f);
  r0[t] = acc*w2[t*2 + 0]; r1[t] = acc*w2[t*2 + 1];
  __syncthreads();
  for (int off = 64; off > 0; off >>= 1){
    if (t < off){ r0[t] += r0[t + off]; r1[t] += r1[t + off]; }
    __syncthreads();
  }
  if (t == 0){ out[g*2 + 0] = r0[0] + b2[0]; out[g*2 + 1] = r1[0] + b2[1]; }
}

extern "C" void kernel_launch(void* const* d_in, const int* in_sizes, int n_in,
                              void* d_out, int out_size, void* d_ws, size_t ws_size,
                              hipStream_t stream) {
  const float* x        = (const float*)d_in[0];
  const int*   ei       = (const int*)  d_in[1];
  const int*   batch    = (const int*)  d_in[2];
  const float* gw1[4] = {(const float*)d_in[3],  (const float*)d_in[7],  (const float*)d_in[11], (const float*)d_in[15]};
  const float* gb1[4] = {(const float*)d_in[4],  (const float*)d_in[8],  (const float*)d_in[12], (const float*)d_in[16]};
  const float* gw2[4] = {(const float*)d_in[5],  (const float*)d_in[9],  (const float*)d_in[13], (const float*)d_in[17]};
  const float* gb2[4] = {(const float*)d_in[6],  (const float*)d_in[10], (const float*)d_in[14], (const float*)d_in[18]};
  const float* bng[5] = {(const float*)d_in[19], (const float*)d_in[21], (const float*)d_in[23], (const float*)d_in[25], (const float*)d_in[27]};
  const float* bnb[5] = {(const float*)d_in[20], (const float*)d_in[22], (const float*)d_in[24], (const float*)d_in[26], (const float*)d_in[28]};
  const float* gat_w    = (const float*)d_in[29];
  const float* gat_asrc = (const float*)d_in[30];
  const float* gat_adst = (const float*)d_in[31];
  const float* gat_bias = (const float*)d_in[32];
  const float* gate_w   = (const float*)d_in[33];
  const float* gate_b   = (const float*)d_in[34];
  const float* fc1_w    = (const float*)d_in[35];
  const float* fc1_b    = (const float*)d_in[36];
  const float* fc2_w    = (const float*)d_in[37];
  const float* fc2_b    = (const float*)d_in[38];
  const int* src = ei;
  const int* dst = ei + NE;

  char* wsb = (char*)d_ws;
  size_t off = 0;
  auto take = [&](size_t bytes) -> void* {
    void* p = wsb + off;
    off = (off + bytes + 255) & ~(size_t)255;
    return p;
  };
  unsigned short* hpre  = (unsigned short*)take((size_t)NN*512*2);   // pre-BN bf16
  unsigned short* hb    = (unsigned short*)take((size_t)NN*512*2);   // post-BN bf16
  unsigned short* zh    = (unsigned short*)take((size_t)NN*1024*2);  // z16 | hid16; contiguous = xh16
  unsigned short* z16   = zh;
  unsigned short* hid16 = zh + (size_t)NN*512;
  unsigned short* xh16  = zh;
  unsigned short* xb    = (unsigned short*)take((size_t)NN*128*2);
  unsigned short* wt    = (unsigned short*)take((size_t)1000000*2);
  double* statsA = (double*)take(2560*8);
  float*  a_s    = (float*) take((size_t)NN*8*4);
  float*  a_d    = (float*) take((size_t)NN*8*4);
  float*  logit  = (float*) take((size_t)NN*4);
  float*  pooled = (float*) take((size_t)NG*128*4);
  // graph ints: deg, cnt, gdeg contiguous (one memset), then rest
  int*    deg    = (int*)   take((size_t)NN*4);
  int*    cnt    = (int*)   take((size_t)NN*4);
  int*    gdeg   = (int*)   take((size_t)NG*4);
  int*    rowptr = (int*)   take((size_t)(NN+1)*4);
  int*    gptr   = (int*)   take((size_t)(NG+1)*4);
  int*    csrc   = (int*)   take((size_t)NE*4);
  (void)ws_size; (void)n_in; (void)in_sizes; (void)out_size;

  unsigned short* wt_g1w1 = wt;
  unsigned short* wt_g1w2 = wt_g1w1 + 128*128;
  unsigned short* wt_g2w1 = wt_g1w2 + 128*128;
  unsigned short* wt_g2w2 = wt_g2w1 + 256*128;
  unsigned short* wt_g3w1 = wt_g2w2 + 256*256;
  unsigned short* wt_g3w2 = wt_g3w1 + 512*256;
  unsigned short* wt_g4w1 = wt_g3w2 + 512*512;
  unsigned short* wt_g4w2 = wt_g4w1 + 256*512;
  unsigned short* wt_gat  = wt_g4w2 + 256*256;

  // BN stats regions (zeroed once): d = 128,256,512,256,128
  double* st1 = statsA + 0;
  double* st2 = statsA + 256;
  double* st3 = statsA + 768;
  double* st4 = statsA + 1792;
  double* st5 = statsA + 2304;

  // ---- memsets (2 total) ----
  hipMemsetAsync(deg, 0, (size_t)((char*)(gdeg + NG) - (char*)deg), stream);
  hipMemsetAsync(statsA, 0, 2560*8, stream);

  // ---- CSR + graph segments ----
  k_hist2<<<(NE + NN + 255)/256, 256, 0, stream>>>(dst, batch, deg, gdeg);
  k_scan2<<<2, 1024, 0, stream>>>(deg, rowptr, gdeg, gptr);
  k_fill<<<(NE + 255)/256, 256, 0, stream>>>(src, dst, rowptr, cnt, csrc);

  // ---- combined weight prep ----
  {
    WPrep P;
    const float* Ws[9] = {gw1[0], gw2[0], gw1[1], gw2[1], gw1[2], gw2[2], gw1[3], gw2[3], gat_w};
    unsigned short* Wts[9] = {wt_g1w1, wt_g1w2, wt_g2w1, wt_g2w2, wt_g3w1, wt_g3w2, wt_g4w1, wt_g4w2, wt_gat};
    int Ks[9]  = {128, 128, 128, 256, 256, 512, 512, 256, 256};
    int Nns[9] = {128, 128, 256, 256, 512, 512, 256, 256, 1024};
    int cum = 0;
    for (int i = 0; i < 9; i++){ P.W[i] = Ws[i]; P.Wt[i] = Wts[i]; P.K[i] = Ks[i]; P.Nn[i] = Nns[i]; P.colStart[i] = cum; cum += Nns[i]; }
    P.colStart[9] = cum;                  // 3328
    P.x = x; P.xb = (unsigned int*)xb;
    int xblocks = (NN*64 + 255)/256;      // 5000
    k_prep<<<cum + xblocks, 256, 0, stream>>>(P);
  }

  const int GM = (NN + 127) / 128;

  auto bnTail = [&](int d, double* st, const float* g, const float* b, int gate){
    int total8 = NN*d/8;
    if (gate)
      k_bn_relu16<1><<<(total8 + 255)/256, 256, 0, stream>>>(hpre, hb, total8, d-1, d, st, g, b, gate_w, gate_b, logit);
    else
      k_bn_relu16<0><<<(total8 + 255)/256, 256, 0, stream>>>(hpre, hb, total8, d-1, d, st, g, b, nullptr, nullptr, nullptr);
  };

  // GIN layers 1-3: aggregate before w1
  auto ginPre = [&](const unsigned short* hin, int Din, int Dh, int Dout, int li,
                    const unsigned short* w1t, const unsigned short* w2t, double* st){
    k_gin_agg16<0><<<NN, Din/2, 0, stream>>>((const unsigned int*)hin, rowptr, csrc, (unsigned int*)z16, Din/2, nullptr);
    k_gemm_mfma<1,1,0,0><<<dim3(Dh/128, GM), 256, 0, stream>>>(z16, w1t, gb1[li], nullptr, hid16, nullptr, nullptr, nullptr, nullptr, nullptr, NN, Dh, Din);
    k_gemm_mfma<0,1,1,0><<<dim3(Dout/128, GM), 256, 0, stream>>>(hid16, w2t, gb2[li], nullptr, hpre, st, nullptr, nullptr, nullptr, nullptr, NN, Dout, Dh);
    bnTail(Dout, st, bng[li], bnb[li], 0);
  };

  ginPre(xb, 128, 128, 128, 0, wt_g1w1, wt_g1w2, st1);
  ginPre(hb, 128, 256, 256, 1, wt_g2w1, wt_g2w2, st2);
  ginPre(hb, 256, 512, 512, 2, wt_g3w1, wt_g3w2, st3);

  // GIN4: aggregate AFTER w1 (512->256): relu(h@w1 + A(h@w1) + b1)
  {
    k_gemm_mfma<0,1,0,0><<<dim3(256/128, GM), 256, 0, stream>>>(hb, wt_g4w1, nullptr, nullptr, hid16, nullptr, nullptr, nullptr, nullptr, nullptr, NN, 256, 512);
    k_gin_agg16<1><<<NN, 128, 0, stream>>>((const unsigned int*)hid16, rowptr, csrc, (unsigned int*)z16, 128, gb1[3]);
    k_gemm_mfma<0,1,1,0><<<dim3(256/128, GM), 256, 0, stream>>>(z16, wt_g4w2, gb2[3], nullptr, hpre, st4, nullptr, nullptr, nullptr, nullptr, NN, 256, 256);
    bnTail(256, st4, bng[3], bnb[3], 0);
  }

  // ---- GAT (scores fused into GEMM epilogue) ----
  k_gemm_mfma<0,1,0,1><<<dim3(1024/128, GM), 256, 0, stream>>>(hb, wt_gat, nullptr, nullptr, xh16, nullptr, gat_asrc, gat_adst, a_s, a_d, NN, 1024, 256);
  k_gat_node256<<<NN, 256, 0, stream>>>(xh16, a_s, a_d, rowptr, csrc, gat_bias, hpre);
  k_bn_stats16<<<(NN + 63)/64, 128, 0, stream>>>(hpre, 128, st5);
  bnTail(128, st5, bng[4], bnb[4], 1);

  // ---- pooling + head ----
  k_pool16<<<NG, 128, 0, stream>>>(hb, logit, gptr, pooled);
  k_head<<<NG, 128, 0, stream>>>(pooled, fc1_w, fc1_b, fc2_w, fc2_b, (float*)d_out);
}